// Round 5
// baseline (28518.771 us; speedup 1.0000x reference)
//
#include <hip/hip_runtime.h>
#include <hip/hip_fp16.h>
#include <math.h>

#define Bsz 64
#define Tsz 1024
#define Isz 128
#define Hsz 512
#define KH  256   // H/2
#define Osz 10

// ---------------------------------------------------------------------------
// Register-tiled fp32 GEMM: C[M,N] = A[M,K] @ Bw[K,N] + bias[N]
// ---------------------------------------------------------------------------
__global__ __launch_bounds__(256) void gemm_bias_kernel(
    const float* __restrict__ A, const float* __restrict__ Bw,
    const float* __restrict__ bias, float* __restrict__ C,
    int M, int N, int K)
{
  __shared__ float As[32][65];
  const int tid = threadIdx.x;
  const int m0 = blockIdx.x * 64;
  const int n0 = blockIdx.y * 64;
  const int ty = tid >> 4, tx = tid & 15;

  float acc[4][4] = {{0.f}};

  for (int kk = 0; kk < K; kk += 32) {
    __syncthreads();
#pragma unroll
    for (int i = tid; i < 64 * 32; i += 256) {
      int m = i >> 5, k = i & 31;
      As[k][m] = A[(size_t)(m0 + m) * K + kk + k];
    }
    __syncthreads();
#pragma unroll
    for (int k = 0; k < 32; ++k) {
      float a0 = As[k][ty * 4 + 0];
      float a1 = As[k][ty * 4 + 1];
      float a2 = As[k][ty * 4 + 2];
      float a3 = As[k][ty * 4 + 3];
      const float4 bv = *(const float4*)(&Bw[(size_t)(kk + k) * N + n0 + tx * 4]);
      acc[0][0] += a0 * bv.x; acc[0][1] += a0 * bv.y; acc[0][2] += a0 * bv.z; acc[0][3] += a0 * bv.w;
      acc[1][0] += a1 * bv.x; acc[1][1] += a1 * bv.y; acc[1][2] += a1 * bv.z; acc[1][3] += a1 * bv.w;
      acc[2][0] += a2 * bv.x; acc[2][1] += a2 * bv.y; acc[2][2] += a2 * bv.z; acc[2][3] += a2 * bv.w;
      acc[3][0] += a3 * bv.x; acc[3][1] += a3 * bv.y; acc[3][2] += a3 * bv.z; acc[3][3] += a3 * bv.w;
    }
  }

  const float4 bb = *(const float4*)(&bias[n0 + tx * 4]);
#pragma unroll
  for (int i = 0; i < 4; ++i) {
    float4 v;
    v.x = acc[i][0] + bb.x; v.y = acc[i][1] + bb.y;
    v.z = acc[i][2] + bb.z; v.w = acc[i][3] + bb.w;
    *(float4*)(&C[(size_t)(m0 + ty * 4 + i) * N + n0 + tx * 4]) = v;
  }
}

// ---------------------------------------------------------------------------
// f16 helpers + packed dot2
// pack: low 16 = even-index element, high 16 = odd-index element.
// ---------------------------------------------------------------------------
typedef _Float16 hf2_t __attribute__((ext_vector_type(2)));

__device__ __forceinline__ unsigned short f16b(float f) {
  return __half_as_ushort(__float2half_rn(f));
}

__device__ __forceinline__ float dot2(unsigned w, unsigned h, float acc) {
#if __has_builtin(__builtin_amdgcn_fdot2)
  return __builtin_amdgcn_fdot2(__builtin_bit_cast(hf2_t, w),
                                __builtin_bit_cast(hf2_t, h), acc, false);
#else
  float wl = __half2float(__ushort_as_half((unsigned short)(w & 0xffffu)));
  float wh = __half2float(__ushort_as_half((unsigned short)(w >> 16)));
  float hl = __half2float(__ushort_as_half((unsigned short)(h & 0xffffu)));
  float hh_ = __half2float(__ushort_as_half((unsigned short)(h >> 16)));
  return fmaf(wl, hl, fmaf(wh, hh_, acc));
#endif
}

// ---------------------------------------------------------------------------
// Weight repack into chunked-x4 f16-pair layout:
//   element (pair p, col c) of a [P pairs x C cols] pair-matrix is stored at
//   out[(p>>2)*(C*4) + c*4 + (p&3)]
// ---------------------------------------------------------------------------
__global__ __launch_bounds__(256) void pack_p0_kernel(
    const float* __restrict__ W_rec, unsigned* __restrict__ P0)
{
  int i = blockIdx.x * 256 + threadIdx.x;
  if (i >= 256 * Hsz) return;
  int p = i >> 9, j = i & 511;
  unsigned lo = f16b(W_rec[(size_t)j * Hsz + 2 * p]);
  unsigned hi = f16b(W_rec[(size_t)j * Hsz + 2 * p + 1]);
  P0[(size_t)(p >> 2) * (Hsz * 4) + j * 4 + (p & 3)] = lo | (hi << 16);
}

__global__ __launch_bounds__(256) void pack_p1_kernel(
    const float* __restrict__ W1b, unsigned* __restrict__ P1)
{
  int i = blockIdx.x * 256 + threadIdx.x;
  if (i >= 256 * KH) return;
  int p = i >> 8, c = i & 255;
  unsigned lo = f16b(W1b[(size_t)(2 * p) * KH + c]);
  unsigned hi = f16b(W1b[(size_t)(2 * p + 1) * KH + c]);
  P1[(size_t)(p >> 2) * (KH * 4) + c * 4 + (p & 3)] = lo | (hi << 16);
}

__global__ __launch_bounds__(256) void pack_p2_kernel(
    const float* __restrict__ W_tau2, unsigned* __restrict__ P2)
{
  int i = blockIdx.x * 256 + threadIdx.x;
  if (i >= 128 * Hsz) return;
  int p = i >> 9, j = i & 511;
  unsigned lo = f16b(W_tau2[(size_t)(2 * p) * Hsz + j]);
  unsigned hi = f16b(W_tau2[(size_t)(2 * p + 1) * Hsz + j]);
  P2[(size_t)(p >> 2) * (Hsz * 4) + j * 4 + (p & 3)] = lo | (hi << 16);
}

// ---------------------------------------------------------------------------
// Sequential scan. One WG (512 threads) per batch element.
// tau2 weights (32 uint4) + half the tau1 weights (16 uint4) are pinned in
// VGPRs (192 regs), loaded once before the T-loop; drive + remaining tau1
// stream from L2 (1280 B/thread/step vs 2048 unpinned).
// ---------------------------------------------------------------------------
__global__ __launch_bounds__(512, 2) void scan_kernel(
    float* __restrict__ xps,           // in: xp [B,T,H]; out: hs [B,T,H]
    const float* __restrict__ U,       // [B,T,KH] (b_tau1 already added)
    const unsigned* __restrict__ P0,   // chunked [64][512][4]
    const unsigned* __restrict__ P1,   // chunked [64][256][4]
    const unsigned* __restrict__ P2,   // chunked [32][512][4]
    const float* __restrict__ bias,    // [H]
    const float* __restrict__ b_tau2)  // [H]
{
  const int b = blockIdx.x;
  const int tid = threadIdx.x;
  const int hs = tid >> 8;             // tau1 k-half
  const int c  = tid & 255;            // tau1 column

  __shared__ __align__(16) unsigned short hh[2][Hsz];  // packed f16 h, dbuf
  __shared__ __align__(16) unsigned short Ah[KH];      // packed f16 relu(A)
  __shared__ float part[2][KH];

  const float bias_r = bias[tid];
  const float bt2_r  = b_tau2[tid];
  float hold = 0.f;
  hh[0][tid] = 0;                      // f16 +0.0

  float* xprow = xps + (size_t)b * Tsz * Hsz;
  const float* Urow = U + (size_t)b * Tsz * KH;

  const uint4* __restrict__ p0 = (const uint4*)P0 + tid;           // stride 512
  const uint4* __restrict__ p1 = (const uint4*)P1 + hs * 8192 + c; // stride 256
  const uint4* __restrict__ p2 = (const uint4*)P2 + tid;           // stride 512
  const uint4* A4 = (const uint4*)Ah;

  // --- one-time: pin tau2 slice (32 uint4) + first half of tau1 (16 uint4) ---
  uint4 w2r[32], w1r[16];
#pragma unroll
  for (int i = 0; i < 32; ++i) w2r[i] = p2[(size_t)i * 512];
#pragma unroll
  for (int i = 0; i < 16; ++i) w1r[i] = p1[(size_t)i * 256];

  __syncthreads();

  for (int t = 0; t < Tsz; ++t) {
    const uint4* h4 = (const uint4*)hh[t & 1];

    const float xpv = xprow[tid];
    const float Uv = (tid < KH) ? Urow[tid] : 0.f;

    // --- tau1 partial: streamed half first (loads in flight), then pinned ---
    float pa = 0.f, pb = 0.f;
#pragma unroll 8
    for (int i = 16; i < 32; ++i) {
      const uint4 w = p1[(size_t)i * 256];
      const uint4 hv = h4[hs * 32 + i];
      pa = dot2(w.x, hv.x, pa); pb = dot2(w.y, hv.y, pb);
      pa = dot2(w.z, hv.z, pa); pb = dot2(w.w, hv.w, pb);
    }
#pragma unroll
    for (int i = 0; i < 16; ++i) {
      const uint4 w = w1r[i];
      const uint4 hv = h4[hs * 32 + i];
      pa = dot2(w.x, hv.x, pa); pb = dot2(w.y, hv.y, pb);
      pa = dot2(w.z, hv.z, pa); pb = dot2(w.w, hv.w, pb);
    }
    part[hs][c] = pa + pb;
    __syncthreads();                                   // sync1

    if (tid < KH) {
      float a = Uv + part[0][tid] + part[1][tid];
      Ah[tid] = f16b(fmaxf(a, 0.f));
    }
    __syncthreads();                                   // sync2

    // --- tau2: full k=256 for column tid (pinned weights) ---
    float s0 = bt2_r, s1 = 0.f;
#pragma unroll
    for (int i = 0; i < 32; ++i) {
      const uint4 w = w2r[i];
      const uint4 av = A4[i];
      s0 = dot2(w.x, av.x, s0); s1 = dot2(w.y, av.y, s1);
      s0 = dot2(w.z, av.z, s0); s1 = dot2(w.w, av.w, s1);
    }

    // --- drive: full k=512 for column tid (streamed) ---
    float d0 = xpv + bias_r, d1 = 0.f;
#pragma unroll 8
    for (int i = 0; i < 64; ++i) {
      const uint4 w = p0[(size_t)i * 512];
      const uint4 hv = h4[i];
      d0 = dot2(w.x, hv.x, d0); d1 = dot2(w.y, hv.y, d1);
      d0 = dot2(w.z, hv.z, d0); d1 = dot2(w.w, hv.w, d1);
    }

    // --- epilogue: tau, tanh, Euler update ---
    const float tau = 5.0f + 45.0f / (1.0f + __expf(-(s0 + s1)));
    const float e2 = __expf(2.0f * (d0 + d1));
    const float drv = 1.0f - 2.0f / (e2 + 1.0f);       // tanh
    const float hnew = hold + (drv - hold) / tau;
    hold = hnew;
    hh[(t + 1) & 1][tid] = f16b(hnew);
    xprow[tid] = hnew;                                 // hs output (dead xp slot)
    __syncthreads();                                   // sync3

    xprow += Hsz;
    Urow  += KH;
  }
}

// ---------------------------------------------------------------------------
// Epilogue: out[m,o] = hs[m,:] @ W_out[:,o] + b_out[o]
// ---------------------------------------------------------------------------
__global__ __launch_bounds__(256) void outproj_kernel(
    const float* __restrict__ hs, const float* __restrict__ W_out,
    const float* __restrict__ b_out, float* __restrict__ out)
{
  const int m = blockIdx.x * 16 + (threadIdx.x >> 4);
  const int o = threadIdx.x & 15;
  if (o >= Osz) return;
  const float* hrow = hs + (size_t)m * Hsz;
  float acc = b_out[o];
#pragma unroll 8
  for (int kk = 0; kk < Hsz; ++kk)
    acc = fmaf(hrow[kk], W_out[(size_t)kk * Osz + o], acc);
  out[(size_t)m * Osz + o] = acc;
}

// ---------------------------------------------------------------------------
extern "C" void kernel_launch(void* const* d_in, const int* in_sizes, int n_in,
                              void* d_out, int out_size, void* d_ws, size_t ws_size,
                              hipStream_t stream) {
  (void)in_sizes; (void)n_in; (void)out_size; (void)ws_size;

  const float* x      = (const float*)d_in[0];
  const float* W_in   = (const float*)d_in[1];
  const float* b_in   = (const float*)d_in[2];
  const float* W_rec  = (const float*)d_in[3];
  const float* bias   = (const float*)d_in[4];
  const float* W_tau1 = (const float*)d_in[5];
  const float* b_tau1 = (const float*)d_in[6];
  const float* W_tau2 = (const float*)d_in[7];
  const float* b_tau2 = (const float*)d_in[8];
  const float* W_out  = (const float*)d_in[9];
  const float* b_out  = (const float*)d_in[10];
  float* out = (float*)d_out;

  char* ws = (char*)d_ws;
  size_t off = 0;
  float* xps = (float*)(ws + off); off += (size_t)Bsz * Tsz * Hsz * 4;  // 128 MiB
  float* U   = (float*)(ws + off); off += (size_t)Bsz * Tsz * KH * 4;   //  64 MiB
  unsigned* P0 = (unsigned*)(ws + off); off += (size_t)256 * Hsz * 4;   // 512 KiB
  unsigned* P1 = (unsigned*)(ws + off); off += (size_t)256 * KH  * 4;   // 256 KiB
  unsigned* P2 = (unsigned*)(ws + off); off += (size_t)128 * Hsz * 4;   // 256 KiB

  const int M = Bsz * Tsz;  // 65536

  // weight repack (f16 pairs, chunked-x4 layout)
  pack_p0_kernel<<<(256 * Hsz + 255) / 256, 256, 0, stream>>>(W_rec, P0);
  pack_p1_kernel<<<(256 * KH + 255) / 256, 256, 0, stream>>>(
      W_tau1 + (size_t)Hsz * KH, P1);
  pack_p2_kernel<<<(128 * Hsz + 255) / 256, 256, 0, stream>>>(W_tau2, P2);

  // xp = x @ W_in + b_in
  {
    dim3 grid(M / 64, Hsz / 64);
    gemm_bias_kernel<<<grid, 256, 0, stream>>>(x, W_in, b_in, xps, M, Hsz, Isz);
  }
  // U = xp @ W_tau1[:512] + b_tau1
  {
    dim3 grid(M / 64, KH / 64);
    gemm_bias_kernel<<<grid, 256, 0, stream>>>(xps, W_tau1, b_tau1, U, M, KH, Hsz);
  }
  // scan (64 WGs, one per batch element)
  scan_kernel<<<Bsz, 512, 0, stream>>>(xps, U, P0, P1, P2, bias, b_tau2);
  // output projection
  outproj_kernel<<<M / 16, 256, 0, stream>>>(xps, W_out, b_out, out);
}

// Round 6
// 24025.500 us; speedup vs baseline: 1.1870x; 1.1870x over previous
//
#include <hip/hip_runtime.h>
#include <hip/hip_fp16.h>
#include <math.h>

#define Bsz 64
#define Tsz 1024
#define Isz 128
#define Hsz 512
#define KH  256   // H/2
#define Osz 10

// ---------------------------------------------------------------------------
// Register-tiled fp32 GEMM: C[M,N] = A[M,K] @ Bw[K,N] + bias[N]
// ---------------------------------------------------------------------------
__global__ __launch_bounds__(256) void gemm_bias_kernel(
    const float* __restrict__ A, const float* __restrict__ Bw,
    const float* __restrict__ bias, float* __restrict__ C,
    int M, int N, int K)
{
  __shared__ float As[32][65];
  const int tid = threadIdx.x;
  const int m0 = blockIdx.x * 64;
  const int n0 = blockIdx.y * 64;
  const int ty = tid >> 4, tx = tid & 15;

  float acc[4][4] = {{0.f}};

  for (int kk = 0; kk < K; kk += 32) {
    __syncthreads();
#pragma unroll
    for (int i = tid; i < 64 * 32; i += 256) {
      int m = i >> 5, k = i & 31;
      As[k][m] = A[(size_t)(m0 + m) * K + kk + k];
    }
    __syncthreads();
#pragma unroll
    for (int k = 0; k < 32; ++k) {
      float a0 = As[k][ty * 4 + 0];
      float a1 = As[k][ty * 4 + 1];
      float a2 = As[k][ty * 4 + 2];
      float a3 = As[k][ty * 4 + 3];
      const float4 bv = *(const float4*)(&Bw[(size_t)(kk + k) * N + n0 + tx * 4]);
      acc[0][0] += a0 * bv.x; acc[0][1] += a0 * bv.y; acc[0][2] += a0 * bv.z; acc[0][3] += a0 * bv.w;
      acc[1][0] += a1 * bv.x; acc[1][1] += a1 * bv.y; acc[1][2] += a1 * bv.z; acc[1][3] += a1 * bv.w;
      acc[2][0] += a2 * bv.x; acc[2][1] += a2 * bv.y; acc[2][2] += a2 * bv.z; acc[2][3] += a2 * bv.w;
      acc[3][0] += a3 * bv.x; acc[3][1] += a3 * bv.y; acc[3][2] += a3 * bv.z; acc[3][3] += a3 * bv.w;
    }
  }

  const float4 bb = *(const float4*)(&bias[n0 + tx * 4]);
#pragma unroll
  for (int i = 0; i < 4; ++i) {
    float4 v;
    v.x = acc[i][0] + bb.x; v.y = acc[i][1] + bb.y;
    v.z = acc[i][2] + bb.z; v.w = acc[i][3] + bb.w;
    *(float4*)(&C[(size_t)(m0 + ty * 4 + i) * N + n0 + tx * 4]) = v;
  }
}

// ---------------------------------------------------------------------------
// f16 helpers + packed dot2
// ---------------------------------------------------------------------------
typedef _Float16 hf2_t __attribute__((ext_vector_type(2)));

__device__ __forceinline__ unsigned short f16b(float f) {
  return __half_as_ushort(__float2half_rn(f));
}

__device__ __forceinline__ float dot2(unsigned w, unsigned h, float acc) {
#if __has_builtin(__builtin_amdgcn_fdot2)
  return __builtin_amdgcn_fdot2(__builtin_bit_cast(hf2_t, w),
                                __builtin_bit_cast(hf2_t, h), acc, false);
#else
  float wl = __half2float(__ushort_as_half((unsigned short)(w & 0xffffu)));
  float wh = __half2float(__ushort_as_half((unsigned short)(w >> 16)));
  float hl = __half2float(__ushort_as_half((unsigned short)(h & 0xffffu)));
  float hh_ = __half2float(__ushort_as_half((unsigned short)(h >> 16)));
  return fmaf(wl, hl, fmaf(wh, hh_, acc));
#endif
}

// ---------------------------------------------------------------------------
// Weight repack into chunked-x4 f16-pair layout:
//   element (pair p, col c) stored at out[(p>>2)*(C*4) + c*4 + (p&3)]
// ---------------------------------------------------------------------------
__global__ __launch_bounds__(256) void pack_p0_kernel(
    const float* __restrict__ W_rec, unsigned* __restrict__ P0)
{
  int i = blockIdx.x * 256 + threadIdx.x;
  if (i >= 256 * Hsz) return;
  int p = i >> 9, j = i & 511;
  unsigned lo = f16b(W_rec[(size_t)j * Hsz + 2 * p]);
  unsigned hi = f16b(W_rec[(size_t)j * Hsz + 2 * p + 1]);
  P0[(size_t)(p >> 2) * (Hsz * 4) + j * 4 + (p & 3)] = lo | (hi << 16);
}

__global__ __launch_bounds__(256) void pack_p1_kernel(
    const float* __restrict__ W1b, unsigned* __restrict__ P1)
{
  int i = blockIdx.x * 256 + threadIdx.x;
  if (i >= 256 * KH) return;
  int p = i >> 8, c = i & 255;
  unsigned lo = f16b(W1b[(size_t)(2 * p) * KH + c]);
  unsigned hi = f16b(W1b[(size_t)(2 * p + 1) * KH + c]);
  P1[(size_t)(p >> 2) * (KH * 4) + c * 4 + (p & 3)] = lo | (hi << 16);
}

__global__ __launch_bounds__(256) void pack_p2_kernel(
    const float* __restrict__ W_tau2, unsigned* __restrict__ P2)
{
  int i = blockIdx.x * 256 + threadIdx.x;
  if (i >= 128 * Hsz) return;
  int p = i >> 9, j = i & 511;
  unsigned lo = f16b(W_tau2[(size_t)(2 * p) * Hsz + j]);
  unsigned hi = f16b(W_tau2[(size_t)(2 * p + 1) * Hsz + j]);
  P2[(size_t)(p >> 2) * (Hsz * 4) + j * 4 + (p & 3)] = lo | (hi << 16);
}

// ---------------------------------------------------------------------------
// Sequential scan. One WG (512 threads, 8 waves = 2/EU -> 256-VGPR budget via
// amdgpu_waves_per_eu(2,2)) per batch element.
// On-chip pinning: tau2 slice (32 uint4) + tau1 first half (16 uint4) in
// VGPRs (192 regs); last 7 drive chunks (56 KB) in LDS.
// Streamed per step: 57 drive + 16 tau1 chunks = 1168 B/thread (vs 2048 R4).
// ---------------------------------------------------------------------------
__global__ void
__attribute__((amdgpu_flat_work_group_size(512, 512), amdgpu_waves_per_eu(2, 2)))
scan_kernel(
    float* __restrict__ xps,           // in: xp [B,T,H]; out: hs [B,T,H]
    const float* __restrict__ U,       // [B,T,KH] (b_tau1 already added)
    const unsigned* __restrict__ P0,   // chunked [64][512][4]
    const unsigned* __restrict__ P1,   // chunked [64][256][4]
    const unsigned* __restrict__ P2,   // chunked [32][512][4]
    const float* __restrict__ bias,    // [H]
    const float* __restrict__ b_tau2)  // [H]
{
  const int b = blockIdx.x;
  const int tid = threadIdx.x;
  const int hs = tid >> 8;             // tau1 k-half
  const int c  = tid & 255;            // tau1 column

  __shared__ __align__(16) uint4 Wlds[7 * 512];        // 56 KB: drive chunks 57..63
  __shared__ __align__(16) unsigned short hh[2][Hsz];  // packed f16 h, dbuf
  __shared__ __align__(16) unsigned short Ah[KH];      // packed f16 relu(A)
  __shared__ float part[2][KH];

  const float bias_r = bias[tid];
  const float bt2_r  = b_tau2[tid];
  float hold = 0.f;
  hh[0][tid] = 0;                      // f16 +0.0

  float* xprow = xps + (size_t)b * Tsz * Hsz;
  const float* Urow = U + (size_t)b * Tsz * KH;

  const uint4* __restrict__ p0 = (const uint4*)P0 + tid;           // stride 512
  const uint4* __restrict__ p1 = (const uint4*)P1 + hs * 8192 + c; // stride 256
  const uint4* __restrict__ p2 = (const uint4*)P2 + tid;           // stride 512
  const uint4* A4 = (const uint4*)Ah;

  // --- one-time: LDS-stage last 7 drive chunks ---
#pragma unroll
  for (int i = 0; i < 7; ++i)
    Wlds[i * 512 + tid] = p0[(size_t)(57 + i) * 512];

  // --- one-time: VGPR-pin tau2 slice (32 uint4) + tau1 first half (16) ---
  uint4 w2r[32], w1r[16];
#pragma unroll
  for (int i = 0; i < 32; ++i) w2r[i] = p2[(size_t)i * 512];
#pragma unroll
  for (int i = 0; i < 16; ++i) w1r[i] = p1[(size_t)i * 256];

  __syncthreads();

  for (int t = 0; t < Tsz; ++t) {
    const uint4* h4 = (const uint4*)hh[t & 1];

    const float xpv = xprow[tid];
    const float Uv = (tid < KH) ? Urow[tid] : 0.f;

    // --- tau1 partial: streamed half first (loads in flight), then pinned ---
    float pa = 0.f, pb = 0.f;
#pragma unroll 4
    for (int i = 16; i < 32; ++i) {
      const uint4 w = p1[(size_t)i * 256];
      const uint4 hv = h4[hs * 32 + i];
      pa = dot2(w.x, hv.x, pa); pb = dot2(w.y, hv.y, pb);
      pa = dot2(w.z, hv.z, pa); pb = dot2(w.w, hv.w, pb);
    }
#pragma unroll
    for (int i = 0; i < 16; ++i) {
      const uint4 w = w1r[i];
      const uint4 hv = h4[hs * 32 + i];
      pa = dot2(w.x, hv.x, pa); pb = dot2(w.y, hv.y, pb);
      pa = dot2(w.z, hv.z, pa); pb = dot2(w.w, hv.w, pb);
    }
    part[hs][c] = pa + pb;
    __syncthreads();                                   // sync1

    if (tid < KH) {
      float a = Uv + part[0][tid] + part[1][tid];
      Ah[tid] = f16b(fmaxf(a, 0.f));
    }
    __syncthreads();                                   // sync2

    // --- tau2: full k=256 for column tid (pinned weights) ---
    float s0 = bt2_r, s1 = 0.f;
#pragma unroll
    for (int i = 0; i < 32; ++i) {
      const uint4 w = w2r[i];
      const uint4 av = A4[i];
      s0 = dot2(w.x, av.x, s0); s1 = dot2(w.y, av.y, s1);
      s0 = dot2(w.z, av.z, s0); s1 = dot2(w.w, av.w, s1);
    }

    // --- drive: 57 streamed chunks + 7 LDS chunks ---
    float d0 = xpv + bias_r, d1 = 0.f;
#pragma unroll 4
    for (int i = 0; i < 57; ++i) {
      const uint4 w = p0[(size_t)i * 512];
      const uint4 hv = h4[i];
      d0 = dot2(w.x, hv.x, d0); d1 = dot2(w.y, hv.y, d1);
      d0 = dot2(w.z, hv.z, d0); d1 = dot2(w.w, hv.w, d1);
    }
#pragma unroll
    for (int i = 0; i < 7; ++i) {
      const uint4 w = Wlds[i * 512 + tid];
      const uint4 hv = h4[57 + i];
      d0 = dot2(w.x, hv.x, d0); d1 = dot2(w.y, hv.y, d1);
      d0 = dot2(w.z, hv.z, d0); d1 = dot2(w.w, hv.w, d1);
    }

    // --- epilogue: tau, tanh, Euler update ---
    const float tau = 5.0f + 45.0f / (1.0f + __expf(-(s0 + s1)));
    const float e2 = __expf(2.0f * (d0 + d1));
    const float drv = 1.0f - 2.0f / (e2 + 1.0f);       // tanh
    const float hnew = hold + (drv - hold) / tau;
    hold = hnew;
    hh[(t + 1) & 1][tid] = f16b(hnew);
    xprow[tid] = hnew;                                 // hs output (dead xp slot)
    __syncthreads();                                   // sync3

    xprow += Hsz;
    Urow  += KH;
  }
}

// ---------------------------------------------------------------------------
// Epilogue: out[m,o] = hs[m,:] @ W_out[:,o] + b_out[o]
// ---------------------------------------------------------------------------
__global__ __launch_bounds__(256) void outproj_kernel(
    const float* __restrict__ hs, const float* __restrict__ W_out,
    const float* __restrict__ b_out, float* __restrict__ out)
{
  const int m = blockIdx.x * 16 + (threadIdx.x >> 4);
  const int o = threadIdx.x & 15;
  if (o >= Osz) return;
  const float* hrow = hs + (size_t)m * Hsz;
  float acc = b_out[o];
#pragma unroll 8
  for (int kk = 0; kk < Hsz; ++kk)
    acc = fmaf(hrow[kk], W_out[(size_t)kk * Osz + o], acc);
  out[(size_t)m * Osz + o] = acc;
}

// ---------------------------------------------------------------------------
extern "C" void kernel_launch(void* const* d_in, const int* in_sizes, int n_in,
                              void* d_out, int out_size, void* d_ws, size_t ws_size,
                              hipStream_t stream) {
  (void)in_sizes; (void)n_in; (void)out_size; (void)ws_size;

  const float* x      = (const float*)d_in[0];
  const float* W_in   = (const float*)d_in[1];
  const float* b_in   = (const float*)d_in[2];
  const float* W_rec  = (const float*)d_in[3];
  const float* bias   = (const float*)d_in[4];
  const float* W_tau1 = (const float*)d_in[5];
  const float* b_tau1 = (const float*)d_in[6];
  const float* W_tau2 = (const float*)d_in[7];
  const float* b_tau2 = (const float*)d_in[8];
  const float* W_out  = (const float*)d_in[9];
  const float* b_out  = (const float*)d_in[10];
  float* out = (float*)d_out;

  char* ws = (char*)d_ws;
  size_t off = 0;
  float* xps = (float*)(ws + off); off += (size_t)Bsz * Tsz * Hsz * 4;  // 128 MiB
  float* U   = (float*)(ws + off); off += (size_t)Bsz * Tsz * KH * 4;   //  64 MiB
  unsigned* P0 = (unsigned*)(ws + off); off += (size_t)256 * Hsz * 4;   // 512 KiB
  unsigned* P1 = (unsigned*)(ws + off); off += (size_t)256 * KH  * 4;   // 256 KiB
  unsigned* P2 = (unsigned*)(ws + off); off += (size_t)128 * Hsz * 4;   // 256 KiB

  const int M = Bsz * Tsz;  // 65536

  // weight repack (f16 pairs, chunked-x4 layout)
  pack_p0_kernel<<<(256 * Hsz + 255) / 256, 256, 0, stream>>>(W_rec, P0);
  pack_p1_kernel<<<(256 * KH + 255) / 256, 256, 0, stream>>>(
      W_tau1 + (size_t)Hsz * KH, P1);
  pack_p2_kernel<<<(128 * Hsz + 255) / 256, 256, 0, stream>>>(W_tau2, P2);

  // xp = x @ W_in + b_in
  {
    dim3 grid(M / 64, Hsz / 64);
    gemm_bias_kernel<<<grid, 256, 0, stream>>>(x, W_in, b_in, xps, M, Hsz, Isz);
  }
  // U = xp @ W_tau1[:512] + b_tau1
  {
    dim3 grid(M / 64, KH / 64);
    gemm_bias_kernel<<<grid, 256, 0, stream>>>(xps, W_tau1, b_tau1, U, M, KH, Hsz);
  }
  // scan (64 WGs, one per batch element)
  scan_kernel<<<Bsz, 512, 0, stream>>>(xps, U, P0, P1, P2, bias, b_tau2);
  // output projection
  outproj_kernel<<<M / 16, 256, 0, stream>>>(xps, W_out, b_out, out);
}

// Round 7
// 10099.612 us; speedup vs baseline: 2.8237x; 2.3789x over previous
//
#include <hip/hip_runtime.h>
#include <hip/hip_fp16.h>
#include <math.h>

#define Bsz 64
#define Tsz 1024
#define Isz 128
#define Hsz 512
#define KH  256   // H/2
#define Osz 10

// ---------------------------------------------------------------------------
// Register-tiled fp32 GEMM: C[M,N] = A[M,K] @ Bw[K,N] + bias[N]
// ---------------------------------------------------------------------------
__global__ __launch_bounds__(256) void gemm_bias_kernel(
    const float* __restrict__ A, const float* __restrict__ Bw,
    const float* __restrict__ bias, float* __restrict__ C,
    int M, int N, int K)
{
  __shared__ float As[32][65];
  const int tid = threadIdx.x;
  const int m0 = blockIdx.x * 64;
  const int n0 = blockIdx.y * 64;
  const int ty = tid >> 4, tx = tid & 15;

  float acc[4][4] = {{0.f}};

  for (int kk = 0; kk < K; kk += 32) {
    __syncthreads();
#pragma unroll
    for (int i = tid; i < 64 * 32; i += 256) {
      int m = i >> 5, k = i & 31;
      As[k][m] = A[(size_t)(m0 + m) * K + kk + k];
    }
    __syncthreads();
#pragma unroll
    for (int k = 0; k < 32; ++k) {
      float a0 = As[k][ty * 4 + 0];
      float a1 = As[k][ty * 4 + 1];
      float a2 = As[k][ty * 4 + 2];
      float a3 = As[k][ty * 4 + 3];
      const float4 bv = *(const float4*)(&Bw[(size_t)(kk + k) * N + n0 + tx * 4]);
      acc[0][0] += a0 * bv.x; acc[0][1] += a0 * bv.y; acc[0][2] += a0 * bv.z; acc[0][3] += a0 * bv.w;
      acc[1][0] += a1 * bv.x; acc[1][1] += a1 * bv.y; acc[1][2] += a1 * bv.z; acc[1][3] += a1 * bv.w;
      acc[2][0] += a2 * bv.x; acc[2][1] += a2 * bv.y; acc[2][2] += a2 * bv.z; acc[2][3] += a2 * bv.w;
      acc[3][0] += a3 * bv.x; acc[3][1] += a3 * bv.y; acc[3][2] += a3 * bv.z; acc[3][3] += a3 * bv.w;
    }
  }

  const float4 bb = *(const float4*)(&bias[n0 + tx * 4]);
#pragma unroll
  for (int i = 0; i < 4; ++i) {
    float4 v;
    v.x = acc[i][0] + bb.x; v.y = acc[i][1] + bb.y;
    v.z = acc[i][2] + bb.z; v.w = acc[i][3] + bb.w;
    *(float4*)(&C[(size_t)(m0 + ty * 4 + i) * N + n0 + tx * 4]) = v;
  }
}

// ---------------------------------------------------------------------------
// f16 helpers + packed dot2 / i8 dot4
// ---------------------------------------------------------------------------
typedef _Float16 hf2_t __attribute__((ext_vector_type(2)));

__device__ __forceinline__ unsigned short f16b(float f) {
  return __half_as_ushort(__float2half_rn(f));
}

__device__ __forceinline__ float dot2(unsigned w, unsigned h, float acc) {
#if __has_builtin(__builtin_amdgcn_fdot2)
  return __builtin_amdgcn_fdot2(__builtin_bit_cast(hf2_t, w),
                                __builtin_bit_cast(hf2_t, h), acc, false);
#else
  float wl = __half2float(__ushort_as_half((unsigned short)(w & 0xffffu)));
  float wh = __half2float(__ushort_as_half((unsigned short)(w >> 16)));
  float hl = __half2float(__ushort_as_half((unsigned short)(h & 0xffffu)));
  float hh_ = __half2float(__ushort_as_half((unsigned short)(h >> 16)));
  return fmaf(wl, hl, fmaf(wh, hh_, acc));
#endif
}

__device__ __forceinline__ int dot4i8(int a, int b, int acc) {
#if __has_builtin(__builtin_amdgcn_sdot4)
  return __builtin_amdgcn_sdot4(a, b, acc, false);
#else
  acc += ((a << 24) >> 24) * ((b << 24) >> 24);
  acc += ((a << 16) >> 24) * ((b << 16) >> 24);
  acc += ((a << 8)  >> 24) * ((b << 8)  >> 24);
  acc += (a >> 24) * (b >> 24);
  return acc;
#endif
}

// ---------------------------------------------------------------------------
// f16 weight repack, chunked-x4 pair layout:
//   element (pair p, col c) stored at out[(p>>2)*(C*4) + c*4 + (p&3)]
// ---------------------------------------------------------------------------
__global__ __launch_bounds__(256) void pack_p0_kernel(
    const float* __restrict__ W_rec, unsigned* __restrict__ P0)
{
  int i = blockIdx.x * 256 + threadIdx.x;
  if (i >= 256 * Hsz) return;
  int p = i >> 9, j = i & 511;
  unsigned lo = f16b(W_rec[(size_t)j * Hsz + 2 * p]);
  unsigned hi = f16b(W_rec[(size_t)j * Hsz + 2 * p + 1]);
  P0[(size_t)(p >> 2) * (Hsz * 4) + j * 4 + (p & 3)] = lo | (hi << 16);
}

__global__ __launch_bounds__(256) void pack_p2_kernel(
    const float* __restrict__ W_tau2, unsigned* __restrict__ P2)
{
  int i = blockIdx.x * 256 + threadIdx.x;
  if (i >= 128 * Hsz) return;
  int p = i >> 9, j = i & 511;
  unsigned lo = f16b(W_tau2[(size_t)(2 * p) * Hsz + j]);
  unsigned hi = f16b(W_tau2[(size_t)(2 * p + 1) * Hsz + j]);
  P2[(size_t)(p >> 2) * (Hsz * 4) + j * 4 + (p & 3)] = lo | (hi << 16);
}

// ---------------------------------------------------------------------------
// tau1 i8 quantization (per-column symmetric scale).
// CS1[c] = max_j |W1b[j][c]|  (j over 512)
// ---------------------------------------------------------------------------
__global__ __launch_bounds__(256) void tau1_scale_kernel(
    const float* __restrict__ W1b, float* __restrict__ CS1)
{
  const int c = threadIdx.x;  // 256
  float m = 0.f;
  for (int j = 0; j < Hsz; ++j)
    m = fmaxf(m, fabsf(W1b[(size_t)j * KH + c]));
  CS1[c] = m;
}

// Q1 layout: uint4 group gg = hs*16+g (32 groups), col c (256). Dword di of
// group gg covers j = hs*256 + 16*g + 4*di + [0..4). Output dword index
// equals the flat thread index i = gg*1024 + c*4 + di.
__global__ __launch_bounds__(256) void tau1_quant_kernel(
    const float* __restrict__ W1b, const float* __restrict__ CS1,
    unsigned* __restrict__ Q1)
{
  int i = blockIdx.x * 256 + threadIdx.x;  // 32768 dwords
  if (i >= 32 * 256 * 4) return;
  int di = i & 3, c = (i >> 2) & 255, gg = i >> 10;
  int hs = gg >> 4, g = gg & 15;
  int j0 = hs * 256 + 16 * g + 4 * di;
  float ma = CS1[c];
  float r = (ma > 0.f) ? (127.f / ma) : 0.f;
  unsigned out = 0;
#pragma unroll
  for (int e = 0; e < 4; ++e) {
    int q = __float2int_rn(W1b[(size_t)(j0 + e) * KH + c] * r);
    out |= ((unsigned)(q & 255)) << (8 * e);
  }
  Q1[i] = out;
}

// ---------------------------------------------------------------------------
// Sequential scan. One WG (512 threads) per batch element — R4 structure
// (VGPR ~44, no pinned reg arrays: R5/R6 showed the allocator spills them).
// Byte cuts vs R4: 7 drive chunks pinned in LDS (56 KB), tau1 in i8 with
// per-column scales (h is exactly |h|<=1 so fixed 127 scale on h).
// Streamed/thread/step: 912(drive f16) + 256(tau1 i8) + 512(tau2 f16) = 1680B.
// ---------------------------------------------------------------------------
__global__ __launch_bounds__(512) void scan_kernel(
    float* __restrict__ xps,           // in: xp [B,T,H]; out: hs [B,T,H]
    const float* __restrict__ U,       // [B,T,KH] (b_tau1 already added)
    const unsigned* __restrict__ P0,   // chunked [64][512][4] f16 pairs
    const unsigned* __restrict__ P2,   // chunked [32][512][4] f16 pairs
    const unsigned* __restrict__ Q1,   // i8 [32 groups][256 cols][4 dwords]
    const float* __restrict__ CS1,     // [256] per-col maxabs
    const float* __restrict__ bias,    // [H]
    const float* __restrict__ b_tau2)  // [H]
{
  const int b = blockIdx.x;
  const int tid = threadIdx.x;
  const int hs = tid >> 8;             // tau1 k-half
  const int c  = tid & 255;            // tau1 column

  __shared__ __align__(16) uint4 Wlds[7 * 512];        // 56 KB drive chunks 57..63
  __shared__ __align__(16) unsigned short hh[2][Hsz];  // packed f16 h, dbuf
  __shared__ __align__(16) unsigned short Ah[KH];      // packed f16 relu(A)
  __shared__ __align__(16) int Hq[128];                // i8 h (512 bytes)
  __shared__ int parti[2][KH];

  const float bias_r = bias[tid];
  const float bt2_r  = b_tau2[tid];
  const float csr = CS1[c] * (1.0f / 16129.0f);        // maxabs / 127^2
  float hold = 0.f;
  hh[0][tid] = 0;                      // f16 +0.0
  if (tid < 128) Hq[tid] = 0;

  float* xprow = xps + (size_t)b * Tsz * Hsz;
  const float* Urow = U + (size_t)b * Tsz * KH;

  const uint4* __restrict__ p0 = (const uint4*)P0 + tid;                 // stride 512
  const uint4* __restrict__ p2 = (const uint4*)P2 + tid;                 // stride 512
  const uint4* __restrict__ q1 = (const uint4*)Q1 + (size_t)(hs * 16) * 256 + c; // stride 256
  const uint4* A4  = (const uint4*)Ah;
  const uint4* Hq4 = (const uint4*)Hq;

  // --- one-time: LDS-stage last 7 drive chunks ---
#pragma unroll
  for (int i = 0; i < 7; ++i)
    Wlds[i * 512 + tid] = p0[(size_t)(57 + i) * 512];

  __syncthreads();

  for (int t = 0; t < Tsz; ++t) {
    const uint4* h4 = (const uint4*)hh[t & 1];

    const float xpv = xprow[tid];
    const float Uv = (tid < KH) ? Urow[tid] : 0.f;

    // --- tau1 partial (i8): this thread's 256-element k-half of column c ---
    int a0 = 0, a1 = 0;
#pragma unroll
    for (int g = 0; g < 16; ++g) {
      const uint4 w  = q1[(size_t)g * 256];
      const uint4 hv = Hq4[hs * 16 + g];
      a0 = dot4i8((int)w.x, (int)hv.x, a0); a1 = dot4i8((int)w.y, (int)hv.y, a1);
      a0 = dot4i8((int)w.z, (int)hv.z, a0); a1 = dot4i8((int)w.w, (int)hv.w, a1);
    }
    parti[hs][c] = a0 + a1;
    __syncthreads();                                   // sync1

    if (tid < KH) {
      float a = Uv + (float)(parti[0][tid] + parti[1][tid]) * csr;
      Ah[tid] = f16b(fmaxf(a, 0.f));
    }
    __syncthreads();                                   // sync2

    // --- tau2: full k=256 for column tid (streamed f16) ---
    float s0 = bt2_r, s1 = 0.f;
#pragma unroll 8
    for (int i = 0; i < 32; ++i) {
      const uint4 w = p2[(size_t)i * 512];
      const uint4 av = A4[i];
      s0 = dot2(w.x, av.x, s0); s1 = dot2(w.y, av.y, s1);
      s0 = dot2(w.z, av.z, s0); s1 = dot2(w.w, av.w, s1);
    }

    // --- drive: 57 streamed chunks + 7 LDS chunks ---
    float d0 = xpv + bias_r, d1 = 0.f;
#pragma unroll 4
    for (int i = 0; i < 57; ++i) {
      const uint4 w = p0[(size_t)i * 512];
      const uint4 hv = h4[i];
      d0 = dot2(w.x, hv.x, d0); d1 = dot2(w.y, hv.y, d1);
      d0 = dot2(w.z, hv.z, d0); d1 = dot2(w.w, hv.w, d1);
    }
#pragma unroll
    for (int i = 0; i < 7; ++i) {
      const uint4 w = Wlds[i * 512 + tid];
      const uint4 hv = h4[57 + i];
      d0 = dot2(w.x, hv.x, d0); d1 = dot2(w.y, hv.y, d1);
      d0 = dot2(w.z, hv.z, d0); d1 = dot2(w.w, hv.w, d1);
    }

    // --- epilogue: tau, tanh, Euler update ---
    const float tau = 5.0f + 45.0f / (1.0f + __expf(-(s0 + s1)));
    const float e2 = __expf(2.0f * (d0 + d1));
    const float drv = 1.0f - 2.0f / (e2 + 1.0f);       // tanh
    const float hnew = hold + (drv - hold) / tau;
    hold = hnew;
    hh[(t + 1) & 1][tid] = f16b(hnew);
    ((char*)Hq)[tid] = (char)(__float2int_rn(hnew * 127.f) & 255);
    xprow[tid] = hnew;                                 // hs output (dead xp slot)
    __syncthreads();                                   // sync3

    xprow += Hsz;
    Urow  += KH;
  }
}

// ---------------------------------------------------------------------------
// Epilogue: out[m,o] = hs[m,:] @ W_out[:,o] + b_out[o]
// ---------------------------------------------------------------------------
__global__ __launch_bounds__(256) void outproj_kernel(
    const float* __restrict__ hs, const float* __restrict__ W_out,
    const float* __restrict__ b_out, float* __restrict__ out)
{
  const int m = blockIdx.x * 16 + (threadIdx.x >> 4);
  const int o = threadIdx.x & 15;
  if (o >= Osz) return;
  const float* hrow = hs + (size_t)m * Hsz;
  float acc = b_out[o];
#pragma unroll 8
  for (int kk = 0; kk < Hsz; ++kk)
    acc = fmaf(hrow[kk], W_out[(size_t)kk * Osz + o], acc);
  out[(size_t)m * Osz + o] = acc;
}

// ---------------------------------------------------------------------------
extern "C" void kernel_launch(void* const* d_in, const int* in_sizes, int n_in,
                              void* d_out, int out_size, void* d_ws, size_t ws_size,
                              hipStream_t stream) {
  (void)in_sizes; (void)n_in; (void)out_size; (void)ws_size;

  const float* x      = (const float*)d_in[0];
  const float* W_in   = (const float*)d_in[1];
  const float* b_in   = (const float*)d_in[2];
  const float* W_rec  = (const float*)d_in[3];
  const float* bias   = (const float*)d_in[4];
  const float* W_tau1 = (const float*)d_in[5];
  const float* b_tau1 = (const float*)d_in[6];
  const float* W_tau2 = (const float*)d_in[7];
  const float* b_tau2 = (const float*)d_in[8];
  const float* W_out  = (const float*)d_in[9];
  const float* b_out  = (const float*)d_in[10];
  float* out = (float*)d_out;

  char* ws = (char*)d_ws;
  size_t off = 0;
  float* xps = (float*)(ws + off); off += (size_t)Bsz * Tsz * Hsz * 4;  // 128 MiB
  float* U   = (float*)(ws + off); off += (size_t)Bsz * Tsz * KH * 4;   //  64 MiB
  unsigned* P0 = (unsigned*)(ws + off); off += (size_t)256 * Hsz * 4;   // 512 KiB
  unsigned* P2 = (unsigned*)(ws + off); off += (size_t)128 * Hsz * 4;   // 256 KiB
  unsigned* Q1 = (unsigned*)(ws + off); off += (size_t)32 * 256 * 4 * 4;// 128 KiB
  float* CS1   = (float*)(ws + off); off += 256 * 4;                    //   1 KiB

  const float* W1b = W_tau1 + (size_t)Hsz * KH;  // rows 512..1023

  const int M = Bsz * Tsz;  // 65536

  // weight repack
  pack_p0_kernel<<<(256 * Hsz + 255) / 256, 256, 0, stream>>>(W_rec, P0);
  pack_p2_kernel<<<(128 * Hsz + 255) / 256, 256, 0, stream>>>(W_tau2, P2);
  tau1_scale_kernel<<<1, 256, 0, stream>>>(W1b, CS1);
  tau1_quant_kernel<<<128, 256, 0, stream>>>(W1b, CS1, Q1);

  // xp = x @ W_in + b_in
  {
    dim3 grid(M / 64, Hsz / 64);
    gemm_bias_kernel<<<grid, 256, 0, stream>>>(x, W_in, b_in, xps, M, Hsz, Isz);
  }
  // U = xp @ W_tau1[:512] + b_tau1
  {
    dim3 grid(M / 64, KH / 64);
    gemm_bias_kernel<<<grid, 256, 0, stream>>>(xps, W_tau1, b_tau1, U, M, KH, Hsz);
  }
  // scan (64 WGs, one per batch element)
  scan_kernel<<<Bsz, 512, 0, stream>>>(xps, U, P0, P2, Q1, CS1, bias, b_tau2);
  // output projection
  outproj_kernel<<<M / 16, 256, 0, stream>>>(xps, W_out, b_out, out);
}

// Round 8
// 8194.023 us; speedup vs baseline: 3.4804x; 1.2326x over previous
//
#include <hip/hip_runtime.h>
#include <hip/hip_fp16.h>
#include <math.h>

#define Bsz 64
#define Tsz 1024
#define Isz 128
#define Hsz 512
#define KH  256   // H/2
#define Osz 10

// ---------------------------------------------------------------------------
// Register-tiled fp32 GEMM: C[M,N] = A[M,K] @ Bw[K,N] + bias[N]
// ---------------------------------------------------------------------------
__global__ __launch_bounds__(256) void gemm_bias_kernel(
    const float* __restrict__ A, const float* __restrict__ Bw,
    const float* __restrict__ bias, float* __restrict__ C,
    int M, int N, int K)
{
  __shared__ float As[32][65];
  const int tid = threadIdx.x;
  const int m0 = blockIdx.x * 64;
  const int n0 = blockIdx.y * 64;
  const int ty = tid >> 4, tx = tid & 15;

  float acc[4][4] = {{0.f}};

  for (int kk = 0; kk < K; kk += 32) {
    __syncthreads();
#pragma unroll
    for (int i = tid; i < 64 * 32; i += 256) {
      int m = i >> 5, k = i & 31;
      As[k][m] = A[(size_t)(m0 + m) * K + kk + k];
    }
    __syncthreads();
#pragma unroll
    for (int k = 0; k < 32; ++k) {
      float a0 = As[k][ty * 4 + 0];
      float a1 = As[k][ty * 4 + 1];
      float a2 = As[k][ty * 4 + 2];
      float a3 = As[k][ty * 4 + 3];
      const float4 bv = *(const float4*)(&Bw[(size_t)(kk + k) * N + n0 + tx * 4]);
      acc[0][0] += a0 * bv.x; acc[0][1] += a0 * bv.y; acc[0][2] += a0 * bv.z; acc[0][3] += a0 * bv.w;
      acc[1][0] += a1 * bv.x; acc[1][1] += a1 * bv.y; acc[1][2] += a1 * bv.z; acc[1][3] += a1 * bv.w;
      acc[2][0] += a2 * bv.x; acc[2][1] += a2 * bv.y; acc[2][2] += a2 * bv.z; acc[2][3] += a2 * bv.w;
      acc[3][0] += a3 * bv.x; acc[3][1] += a3 * bv.y; acc[3][2] += a3 * bv.z; acc[3][3] += a3 * bv.w;
    }
  }

  const float4 bb = *(const float4*)(&bias[n0 + tx * 4]);
#pragma unroll
  for (int i = 0; i < 4; ++i) {
    float4 v;
    v.x = acc[i][0] + bb.x; v.y = acc[i][1] + bb.y;
    v.z = acc[i][2] + bb.z; v.w = acc[i][3] + bb.w;
    *(float4*)(&C[(size_t)(m0 + ty * 4 + i) * N + n0 + tx * 4]) = v;
  }
}

// ---------------------------------------------------------------------------
// f16 helpers + packed dot2 / i8 dot4
// ---------------------------------------------------------------------------
typedef _Float16 hf2_t __attribute__((ext_vector_type(2)));

__device__ __forceinline__ unsigned short f16b(float f) {
  return __half_as_ushort(__float2half_rn(f));
}

__device__ __forceinline__ float dot2(unsigned w, unsigned h, float acc) {
#if __has_builtin(__builtin_amdgcn_fdot2)
  return __builtin_amdgcn_fdot2(__builtin_bit_cast(hf2_t, w),
                                __builtin_bit_cast(hf2_t, h), acc, false);
#else
  float wl = __half2float(__ushort_as_half((unsigned short)(w & 0xffffu)));
  float wh = __half2float(__ushort_as_half((unsigned short)(w >> 16)));
  float hl = __half2float(__ushort_as_half((unsigned short)(h & 0xffffu)));
  float hh_ = __half2float(__ushort_as_half((unsigned short)(h >> 16)));
  return fmaf(wl, hl, fmaf(wh, hh_, acc));
#endif
}

__device__ __forceinline__ int dot4i8(int a, int b, int acc) {
#if __has_builtin(__builtin_amdgcn_sdot4)
  return __builtin_amdgcn_sdot4(a, b, acc, false);
#else
  acc += ((a << 24) >> 24) * ((b << 24) >> 24);
  acc += ((a << 16) >> 24) * ((b << 16) >> 24);
  acc += ((a << 8)  >> 24) * ((b << 8)  >> 24);
  acc += (a >> 24) * (b >> 24);
  return acc;
#endif
}

// ---------------------------------------------------------------------------
// f16 weight repack, chunked-x4 pair layout:
//   element (pair p, col c) stored at out[(p>>2)*(C*4) + c*4 + (p&3)]
// ---------------------------------------------------------------------------
__global__ __launch_bounds__(256) void pack_p0_kernel(
    const float* __restrict__ W_rec, unsigned* __restrict__ P0)
{
  int i = blockIdx.x * 256 + threadIdx.x;
  if (i >= 256 * Hsz) return;
  int p = i >> 9, j = i & 511;
  unsigned lo = f16b(W_rec[(size_t)j * Hsz + 2 * p]);
  unsigned hi = f16b(W_rec[(size_t)j * Hsz + 2 * p + 1]);
  P0[(size_t)(p >> 2) * (Hsz * 4) + j * 4 + (p & 3)] = lo | (hi << 16);
}

__global__ __launch_bounds__(256) void pack_p2_kernel(
    const float* __restrict__ W_tau2, unsigned* __restrict__ P2)
{
  int i = blockIdx.x * 256 + threadIdx.x;
  if (i >= 128 * Hsz) return;
  int p = i >> 9, j = i & 511;
  unsigned lo = f16b(W_tau2[(size_t)(2 * p) * Hsz + j]);
  unsigned hi = f16b(W_tau2[(size_t)(2 * p + 1) * Hsz + j]);
  P2[(size_t)(p >> 2) * (Hsz * 4) + j * 4 + (p & 3)] = lo | (hi << 16);
}

// ---------------------------------------------------------------------------
// tau1 i8 quantization (per-column symmetric scale).
// ---------------------------------------------------------------------------
__global__ __launch_bounds__(256) void tau1_scale_kernel(
    const float* __restrict__ W1b, float* __restrict__ CS1)
{
  const int c = threadIdx.x;  // 256
  float m = 0.f;
  for (int j = 0; j < Hsz; ++j)
    m = fmaxf(m, fabsf(W1b[(size_t)j * KH + c]));
  CS1[c] = m;
}

// Q1 layout: uint4 group gg = hs*16+g (32 groups), col c (256). Dword di of
// group gg covers j = hs*256 + 16*g + 4*di + [0..4).
__global__ __launch_bounds__(256) void tau1_quant_kernel(
    const float* __restrict__ W1b, const float* __restrict__ CS1,
    unsigned* __restrict__ Q1)
{
  int i = blockIdx.x * 256 + threadIdx.x;  // 32768 dwords
  if (i >= 32 * 256 * 4) return;
  int di = i & 3, c = (i >> 2) & 255, gg = i >> 10;
  int hs = gg >> 4, g = gg & 15;
  int j0 = hs * 256 + 16 * g + 4 * di;
  float ma = CS1[c];
  float r = (ma > 0.f) ? (127.f / ma) : 0.f;
  unsigned out = 0;
#pragma unroll
  for (int e = 0; e < 4; ++e) {
    int q = __float2int_rn(W1b[(size_t)(j0 + e) * KH + c] * r);
    out |= ((unsigned)(q & 255)) << (8 * e);
  }
  Q1[i] = out;
}

// ---------------------------------------------------------------------------
// Sequential scan. One WG (512 threads) per batch element — R4 issue
// structure (unroll 8 on ALL streamed loops: 8 in-flight 16B loads/wave are
// needed to hide ~300cyc L2 latency; R7's unroll-4 cost 40% stream BW).
// Byte cuts vs R4: 7 drive chunks pinned in LDS (56 KB), tau1 in i8.
// Streamed/thread/step: 912(drive f16) + 256(tau1 i8) + 512(tau2 f16) = 1680B.
// ---------------------------------------------------------------------------
__global__ __launch_bounds__(512) void scan_kernel(
    float* __restrict__ xps,           // in: xp [B,T,H]; out: hs [B,T,H]
    const float* __restrict__ U,       // [B,T,KH] (b_tau1 already added)
    const unsigned* __restrict__ P0,   // chunked [64][512][4] f16 pairs
    const unsigned* __restrict__ P2,   // chunked [32][512][4] f16 pairs
    const unsigned* __restrict__ Q1,   // i8 [32 groups][256 cols][4 dwords]
    const float* __restrict__ CS1,     // [256] per-col maxabs
    const float* __restrict__ bias,    // [H]
    const float* __restrict__ b_tau2)  // [H]
{
  const int b = blockIdx.x;
  const int tid = threadIdx.x;
  const int hs = tid >> 8;             // tau1 k-half
  const int c  = tid & 255;            // tau1 column

  __shared__ __align__(16) uint4 Wlds[7 * 512];        // 56 KB drive chunks 57..63
  __shared__ __align__(16) unsigned short hh[2][Hsz];  // packed f16 h, dbuf
  __shared__ __align__(16) unsigned short Ah[KH];      // packed f16 relu(A)
  __shared__ __align__(16) int Hq[128];                // i8 h (512 bytes)
  __shared__ int parti[2][KH];

  const float bias_r = bias[tid];
  const float bt2_r  = b_tau2[tid];
  const float csr = CS1[c] * (1.0f / 16129.0f);        // maxabs / 127^2
  float hold = 0.f;
  hh[0][tid] = 0;                      // f16 +0.0
  if (tid < 128) Hq[tid] = 0;

  float* xprow = xps + (size_t)b * Tsz * Hsz;
  const float* Urow = U + (size_t)b * Tsz * KH;

  const uint4* __restrict__ p0 = (const uint4*)P0 + tid;                 // stride 512
  const uint4* __restrict__ p2 = (const uint4*)P2 + tid;                 // stride 512
  const uint4* __restrict__ q1 = (const uint4*)Q1 + (size_t)(hs * 16) * 256 + c; // stride 256
  const uint4* A4  = (const uint4*)Ah;
  const uint4* Hq4 = (const uint4*)Hq;

  // --- one-time: LDS-stage last 7 drive chunks ---
#pragma unroll
  for (int i = 0; i < 7; ++i)
    Wlds[i * 512 + tid] = p0[(size_t)(57 + i) * 512];

  __syncthreads();

  for (int t = 0; t < Tsz; ++t) {
    const uint4* h4 = (const uint4*)hh[t & 1];

    const float xpv = xprow[tid];
    const float Uv = (tid < KH) ? Urow[tid] : 0.f;

    // --- tau1 partial (i8): this thread's 256-element k-half of column c ---
    int a0 = 0, a1 = 0;
#pragma unroll 8
    for (int g = 0; g < 16; ++g) {
      const uint4 w  = q1[(size_t)g * 256];
      const uint4 hv = Hq4[hs * 16 + g];
      a0 = dot4i8((int)w.x, (int)hv.x, a0); a1 = dot4i8((int)w.y, (int)hv.y, a1);
      a0 = dot4i8((int)w.z, (int)hv.z, a0); a1 = dot4i8((int)w.w, (int)hv.w, a1);
    }
    parti[hs][c] = a0 + a1;
    __syncthreads();                                   // sync1

    if (tid < KH) {
      float a = Uv + (float)(parti[0][tid] + parti[1][tid]) * csr;
      Ah[tid] = f16b(fmaxf(a, 0.f));
    }
    __syncthreads();                                   // sync2

    // --- tau2: full k=256 for column tid (streamed f16) ---
    float s0 = bt2_r, s1 = 0.f;
#pragma unroll 8
    for (int i = 0; i < 32; ++i) {
      const uint4 w = p2[(size_t)i * 512];
      const uint4 av = A4[i];
      s0 = dot2(w.x, av.x, s0); s1 = dot2(w.y, av.y, s1);
      s0 = dot2(w.z, av.z, s0); s1 = dot2(w.w, av.w, s1);
    }

    // --- drive: 57 streamed chunks (unroll 8) + 7 LDS chunks ---
    float d0 = xpv + bias_r, d1 = 0.f;
#pragma unroll 8
    for (int i = 0; i < 57; ++i) {
      const uint4 w = p0[(size_t)i * 512];
      const uint4 hv = h4[i];
      d0 = dot2(w.x, hv.x, d0); d1 = dot2(w.y, hv.y, d1);
      d0 = dot2(w.z, hv.z, d0); d1 = dot2(w.w, hv.w, d1);
    }
#pragma unroll
    for (int i = 0; i < 7; ++i) {
      const uint4 w = Wlds[i * 512 + tid];
      const uint4 hv = h4[57 + i];
      d0 = dot2(w.x, hv.x, d0); d1 = dot2(w.y, hv.y, d1);
      d0 = dot2(w.z, hv.z, d0); d1 = dot2(w.w, hv.w, d1);
    }

    // --- epilogue: tau, tanh, Euler update ---
    const float tau = 5.0f + 45.0f / (1.0f + __expf(-(s0 + s1)));
    const float e2 = __expf(2.0f * (d0 + d1));
    const float drv = 1.0f - 2.0f / (e2 + 1.0f);       // tanh
    const float hnew = hold + (drv - hold) / tau;
    hold = hnew;
    hh[(t + 1) & 1][tid] = f16b(hnew);
    ((char*)Hq)[tid] = (char)(__float2int_rn(hnew * 127.f) & 255);
    xprow[tid] = hnew;                                 // hs output (dead xp slot)
    __syncthreads();                                   // sync3

    xprow += Hsz;
    Urow  += KH;
  }
}

// ---------------------------------------------------------------------------
// Epilogue: out[m,o] = hs[m,:] @ W_out[:,o] + b_out[o]
// ---------------------------------------------------------------------------
__global__ __launch_bounds__(256) void outproj_kernel(
    const float* __restrict__ hs, const float* __restrict__ W_out,
    const float* __restrict__ b_out, float* __restrict__ out)
{
  const int m = blockIdx.x * 16 + (threadIdx.x >> 4);
  const int o = threadIdx.x & 15;
  if (o >= Osz) return;
  const float* hrow = hs + (size_t)m * Hsz;
  float acc = b_out[o];
#pragma unroll 8
  for (int kk = 0; kk < Hsz; ++kk)
    acc = fmaf(hrow[kk], W_out[(size_t)kk * Osz + o], acc);
  out[(size_t)m * Osz + o] = acc;
}

// ---------------------------------------------------------------------------
extern "C" void kernel_launch(void* const* d_in, const int* in_sizes, int n_in,
                              void* d_out, int out_size, void* d_ws, size_t ws_size,
                              hipStream_t stream) {
  (void)in_sizes; (void)n_in; (void)out_size; (void)ws_size;

  const float* x      = (const float*)d_in[0];
  const float* W_in   = (const float*)d_in[1];
  const float* b_in   = (const float*)d_in[2];
  const float* W_rec  = (const float*)d_in[3];
  const float* bias   = (const float*)d_in[4];
  const float* W_tau1 = (const float*)d_in[5];
  const float* b_tau1 = (const float*)d_in[6];
  const float* W_tau2 = (const float*)d_in[7];
  const float* b_tau2 = (const float*)d_in[8];
  const float* W_out  = (const float*)d_in[9];
  const float* b_out  = (const float*)d_in[10];
  float* out = (float*)d_out;

  char* ws = (char*)d_ws;
  size_t off = 0;
  float* xps = (float*)(ws + off); off += (size_t)Bsz * Tsz * Hsz * 4;  // 128 MiB
  float* U   = (float*)(ws + off); off += (size_t)Bsz * Tsz * KH * 4;   //  64 MiB
  unsigned* P0 = (unsigned*)(ws + off); off += (size_t)256 * Hsz * 4;   // 512 KiB
  unsigned* P2 = (unsigned*)(ws + off); off += (size_t)128 * Hsz * 4;   // 256 KiB
  unsigned* Q1 = (unsigned*)(ws + off); off += (size_t)32 * 256 * 4 * 4;// 128 KiB
  float* CS1   = (float*)(ws + off); off += 256 * 4;                    //   1 KiB

  const float* W1b = W_tau1 + (size_t)Hsz * KH;  // rows 512..1023

  const int M = Bsz * Tsz;  // 65536

  // weight repack
  pack_p0_kernel<<<(256 * Hsz + 255) / 256, 256, 0, stream>>>(W_rec, P0);
  pack_p2_kernel<<<(128 * Hsz + 255) / 256, 256, 0, stream>>>(W_tau2, P2);
  tau1_scale_kernel<<<1, 256, 0, stream>>>(W1b, CS1);
  tau1_quant_kernel<<<128, 256, 0, stream>>>(W1b, CS1, Q1);

  // xp = x @ W_in + b_in
  {
    dim3 grid(M / 64, Hsz / 64);
    gemm_bias_kernel<<<grid, 256, 0, stream>>>(x, W_in, b_in, xps, M, Hsz, Isz);
  }
  // U = xp @ W_tau1[:512] + b_tau1
  {
    dim3 grid(M / 64, KH / 64);
    gemm_bias_kernel<<<grid, 256, 0, stream>>>(xps, W_tau1, b_tau1, U, M, KH, Hsz);
  }
  // scan (64 WGs, one per batch element)
  scan_kernel<<<Bsz, 512, 0, stream>>>(xps, U, P0, P2, Q1, CS1, bias, b_tau2);
  // output projection
  outproj_kernel<<<M / 16, 256, 0, stream>>>(xps, W_out, b_out, out);
}

// Round 9
// 7093.044 us; speedup vs baseline: 4.0207x; 1.1552x over previous
//
#include <hip/hip_runtime.h>
#include <hip/hip_fp16.h>
#include <math.h>

#define Bsz 64
#define Tsz 1024
#define Isz 128
#define Hsz 512
#define KH  256   // H/2
#define Osz 10
#define NPIN 16   // drive chunks pinned in dynamic LDS (of 64)

// ---------------------------------------------------------------------------
// Register-tiled fp32 GEMM: C[M,N] = A[M,K] @ Bw[K,N] + bias[N]
// ---------------------------------------------------------------------------
__global__ __launch_bounds__(256) void gemm_bias_kernel(
    const float* __restrict__ A, const float* __restrict__ Bw,
    const float* __restrict__ bias, float* __restrict__ C,
    int M, int N, int K)
{
  __shared__ float As[32][65];
  const int tid = threadIdx.x;
  const int m0 = blockIdx.x * 64;
  const int n0 = blockIdx.y * 64;
  const int ty = tid >> 4, tx = tid & 15;

  float acc[4][4] = {{0.f}};

  for (int kk = 0; kk < K; kk += 32) {
    __syncthreads();
#pragma unroll
    for (int i = tid; i < 64 * 32; i += 256) {
      int m = i >> 5, k = i & 31;
      As[k][m] = A[(size_t)(m0 + m) * K + kk + k];
    }
    __syncthreads();
#pragma unroll
    for (int k = 0; k < 32; ++k) {
      float a0 = As[k][ty * 4 + 0];
      float a1 = As[k][ty * 4 + 1];
      float a2 = As[k][ty * 4 + 2];
      float a3 = As[k][ty * 4 + 3];
      const float4 bv = *(const float4*)(&Bw[(size_t)(kk + k) * N + n0 + tx * 4]);
      acc[0][0] += a0 * bv.x; acc[0][1] += a0 * bv.y; acc[0][2] += a0 * bv.z; acc[0][3] += a0 * bv.w;
      acc[1][0] += a1 * bv.x; acc[1][1] += a1 * bv.y; acc[1][2] += a1 * bv.z; acc[1][3] += a1 * bv.w;
      acc[2][0] += a2 * bv.x; acc[2][1] += a2 * bv.y; acc[2][2] += a2 * bv.z; acc[2][3] += a2 * bv.w;
      acc[3][0] += a3 * bv.x; acc[3][1] += a3 * bv.y; acc[3][2] += a3 * bv.z; acc[3][3] += a3 * bv.w;
    }
  }

  const float4 bb = *(const float4*)(&bias[n0 + tx * 4]);
#pragma unroll
  for (int i = 0; i < 4; ++i) {
    float4 v;
    v.x = acc[i][0] + bb.x; v.y = acc[i][1] + bb.y;
    v.z = acc[i][2] + bb.z; v.w = acc[i][3] + bb.w;
    *(float4*)(&C[(size_t)(m0 + ty * 4 + i) * N + n0 + tx * 4]) = v;
  }
}

// ---------------------------------------------------------------------------
// f16 helpers + packed dot2 / i8 dot4
// ---------------------------------------------------------------------------
typedef _Float16 hf2_t __attribute__((ext_vector_type(2)));

__device__ __forceinline__ unsigned short f16b(float f) {
  return __half_as_ushort(__float2half_rn(f));
}

__device__ __forceinline__ float dot2(unsigned w, unsigned h, float acc) {
#if __has_builtin(__builtin_amdgcn_fdot2)
  return __builtin_amdgcn_fdot2(__builtin_bit_cast(hf2_t, w),
                                __builtin_bit_cast(hf2_t, h), acc, false);
#else
  float wl = __half2float(__ushort_as_half((unsigned short)(w & 0xffffu)));
  float wh = __half2float(__ushort_as_half((unsigned short)(w >> 16)));
  float hl = __half2float(__ushort_as_half((unsigned short)(h & 0xffffu)));
  float hh_ = __half2float(__ushort_as_half((unsigned short)(h >> 16)));
  return fmaf(wl, hl, fmaf(wh, hh_, acc));
#endif
}

__device__ __forceinline__ int dot4i8(int a, int b, int acc) {
#if __has_builtin(__builtin_amdgcn_sdot4)
  return __builtin_amdgcn_sdot4(a, b, acc, false);
#else
  acc += ((a << 24) >> 24) * ((b << 24) >> 24);
  acc += ((a << 16) >> 24) * ((b << 16) >> 24);
  acc += ((a << 8)  >> 24) * ((b << 8)  >> 24);
  acc += (a >> 24) * (b >> 24);
  return acc;
#endif
}

// ---------------------------------------------------------------------------
// Drive (W_rec) f16 repack, chunked-x4 pair layout:
//   element (pair p, col c) stored at out[(p>>2)*(C*4) + c*4 + (p&3)]
// ---------------------------------------------------------------------------
__global__ __launch_bounds__(256) void pack_p0_kernel(
    const float* __restrict__ W_rec, unsigned* __restrict__ P0)
{
  int i = blockIdx.x * 256 + threadIdx.x;
  if (i >= 256 * Hsz) return;
  int p = i >> 9, j = i & 511;
  unsigned lo = f16b(W_rec[(size_t)j * Hsz + 2 * p]);
  unsigned hi = f16b(W_rec[(size_t)j * Hsz + 2 * p + 1]);
  P0[(size_t)(p >> 2) * (Hsz * 4) + j * 4 + (p & 3)] = lo | (hi << 16);
}

// ---------------------------------------------------------------------------
// tau1 i8 quantization (per-column symmetric scale).
// ---------------------------------------------------------------------------
__global__ __launch_bounds__(256) void tau1_scale_kernel(
    const float* __restrict__ W1b, float* __restrict__ CS1)
{
  const int c = threadIdx.x;  // 256
  float m = 0.f;
  for (int j = 0; j < Hsz; ++j)
    m = fmaxf(m, fabsf(W1b[(size_t)j * KH + c]));
  CS1[c] = m;
}

// Q1 layout: uint4 group gg = hs*16+g (32 groups), col c (256). Dword di of
// group gg covers j = hs*256 + 16*g + 4*di + [0..4).
__global__ __launch_bounds__(256) void tau1_quant_kernel(
    const float* __restrict__ W1b, const float* __restrict__ CS1,
    unsigned* __restrict__ Q1)
{
  int i = blockIdx.x * 256 + threadIdx.x;  // 32768 dwords
  if (i >= 32 * 256 * 4) return;
  int di = i & 3, c = (i >> 2) & 255, gg = i >> 10;
  int hs = gg >> 4, g = gg & 15;
  int j0 = hs * 256 + 16 * g + 4 * di;
  float ma = CS1[c];
  float r = (ma > 0.f) ? (127.f / ma) : 0.f;
  unsigned out = 0;
#pragma unroll
  for (int e = 0; e < 4; ++e) {
    int q = __float2int_rn(W1b[(size_t)(j0 + e) * KH + c] * r);
    out |= ((unsigned)(q & 255)) << (8 * e);
  }
  Q1[i] = out;
}

// ---------------------------------------------------------------------------
// tau2 i8 quantization (per-column scale on W; A gets per-step dynamic scale).
// ---------------------------------------------------------------------------
__global__ __launch_bounds__(256) void tau2_scale_kernel(
    const float* __restrict__ W_tau2, float* __restrict__ CS2)
{
  const int j = blockIdx.x * 256 + threadIdx.x;  // 512
  float m = 0.f;
  for (int k = 0; k < KH; ++k)
    m = fmaxf(m, fabsf(W_tau2[(size_t)k * Hsz + j]));
  CS2[j] = m;
}

// Q2 layout: uint4 group g (16), col j (512). Dword di of group g covers
// k = 16*g + 4*di + [0..4).  Flat dword index = g*2048 + j*4 + di.
__global__ __launch_bounds__(256) void tau2_quant_kernel(
    const float* __restrict__ W_tau2, const float* __restrict__ CS2,
    unsigned* __restrict__ Q2)
{
  int i = blockIdx.x * 256 + threadIdx.x;  // 32768 dwords
  if (i >= 16 * Hsz * 4) return;
  int di = i & 3, j = (i >> 2) & 511, g = i >> 11;
  int k0 = 16 * g + 4 * di;
  float ma = CS2[j];
  float r = (ma > 0.f) ? (127.f / ma) : 0.f;
  unsigned out = 0;
#pragma unroll
  for (int e = 0; e < 4; ++e) {
    int q = __float2int_rn(W_tau2[(size_t)(k0 + e) * Hsz + j] * r);
    out |= ((unsigned)(q & 255)) << (8 * e);
  }
  Q2[i] = out;
}

// ---------------------------------------------------------------------------
// Sequential scan. One WG (512 threads) per batch element. R8 issue
// structure (unroll 8 on streamed loops). Byte cuts vs R8:
//  - 16 drive chunks (128 KB) pinned in DYNAMIC LDS (needs opt-in attribute)
//  - tau2 in i8: per-col W scale x per-step A scale (LDS atomicMax reduce)
// Streamed/thread/step: 768(drive f16) + 256(tau1 i8) + 256(tau2 i8) = 1280B.
// 4 barriers/step (extra one for the A-scale broadcast).
// ---------------------------------------------------------------------------
__global__ __launch_bounds__(512) void scan_kernel(
    float* __restrict__ xps,           // in: xp [B,T,H]; out: hs [B,T,H]
    const float* __restrict__ U,       // [B,T,KH] (b_tau1 already added)
    const unsigned* __restrict__ P0,   // chunked [64][512][4] f16 pairs
    const unsigned* __restrict__ Q1,   // i8 [32 groups][256 cols][4 dwords]
    const unsigned* __restrict__ Q2,   // i8 [16 groups][512 cols][4 dwords]
    const float* __restrict__ CS1,     // [256] tau1 per-col maxabs
    const float* __restrict__ CS2,     // [512] tau2 per-col maxabs
    const float* __restrict__ bias,    // [H]
    const float* __restrict__ b_tau2)  // [H]
{
  const int b = blockIdx.x;
  const int tid = threadIdx.x;
  const int hs = tid >> 8;             // tau1 k-half
  const int c  = tid & 255;            // tau1 column

  extern __shared__ __align__(16) uint4 Wlds[];        // NPIN*512 uint4 = 128 KB
  __shared__ __align__(16) unsigned short hh[2][Hsz];  // packed f16 h, dbuf
  __shared__ __align__(16) unsigned char Aq[KH];       // i8 A (256 B)
  __shared__ __align__(16) int Hq[128];                // i8 h (512 B)
  __shared__ int parti[2][KH];
  __shared__ int amax_i;

  const float bias_r = bias[tid];
  const float bt2_r  = b_tau2[tid];
  const float csr  = CS1[c]   * (1.0f / 16129.0f);     // tau1 dequant
  const float cs2r = CS2[tid] * (1.0f / 16129.0f);     // tau2 dequant (x amax)
  float hold = 0.f;
  hh[0][tid] = 0;                      // f16 +0.0
  if (tid < 128) Hq[tid] = 0;

  float* xprow = xps + (size_t)b * Tsz * Hsz;
  const float* Urow = U + (size_t)b * Tsz * KH;

  const uint4* __restrict__ p0 = (const uint4*)P0 + tid;                 // stride 512
  const uint4* __restrict__ q1 = (const uint4*)Q1 + (size_t)(hs * 16) * 256 + c; // stride 256
  const uint4* __restrict__ q2 = (const uint4*)Q2 + tid;                 // stride 512
  const uint4* Aq4 = (const uint4*)Aq;
  const uint4* Hq4 = (const uint4*)Hq;

  // --- one-time: stage last NPIN drive chunks into dynamic LDS ---
#pragma unroll
  for (int i = 0; i < NPIN; ++i)
    Wlds[i * 512 + tid] = p0[(size_t)(64 - NPIN + i) * 512];

  __syncthreads();

  for (int t = 0; t < Tsz; ++t) {
    const uint4* h4 = (const uint4*)hh[t & 1];

    if (tid == 0) amax_i = 0;          // safe: prev step's reads ended pre-sync3

    const float xpv = xprow[tid];
    const float Uv = (tid < KH) ? Urow[tid] : 0.f;

    // --- tau1 partial (i8): this thread's 256-element k-half of column c ---
    int a0 = 0, a1 = 0;
#pragma unroll 8
    for (int g = 0; g < 16; ++g) {
      const uint4 w  = q1[(size_t)g * 256];
      const uint4 hv = Hq4[hs * 16 + g];
      a0 = dot4i8((int)w.x, (int)hv.x, a0); a1 = dot4i8((int)w.y, (int)hv.y, a1);
      a0 = dot4i8((int)w.z, (int)hv.z, a0); a1 = dot4i8((int)w.w, (int)hv.w, a1);
    }
    parti[hs][c] = a0 + a1;
    __syncthreads();                                   // sync1

    float aval = 0.f;
    if (tid < KH) {
      aval = fmaxf(Uv + (float)(parti[0][tid] + parti[1][tid]) * csr, 0.f);
      float m = aval;
#pragma unroll
      for (int off = 32; off >= 1; off >>= 1)
        m = fmaxf(m, __shfl_xor(m, off));
      if ((tid & 63) == 0) atomicMax(&amax_i, __float_as_int(m));
    }
    __syncthreads();                                   // sync2

    const float amax = __int_as_float(amax_i);
    if (tid < KH) {
      const float r = (amax > 0.f) ? (127.f / amax) : 0.f;
      Aq[tid] = (unsigned char)__float2int_rn(aval * r);
    }
    __syncthreads();                                   // sync2b

    // --- tau2 (i8): full k=256 for column tid ---
    int s0i = 0, s1i = 0;
#pragma unroll 8
    for (int g = 0; g < 16; ++g) {
      const uint4 w  = q2[(size_t)g * 512];
      const uint4 av = Aq4[g];
      s0i = dot4i8((int)w.x, (int)av.x, s0i); s1i = dot4i8((int)w.y, (int)av.y, s1i);
      s0i = dot4i8((int)w.z, (int)av.z, s0i); s1i = dot4i8((int)w.w, (int)av.w, s1i);
    }
    const float s = bt2_r + (float)(s0i + s1i) * cs2r * amax;

    // --- drive: 48 streamed chunks (unroll 8) + 16 LDS chunks ---
    float d0 = xpv + bias_r, d1 = 0.f;
#pragma unroll 8
    for (int i = 0; i < 64 - NPIN; ++i) {
      const uint4 w = p0[(size_t)i * 512];
      const uint4 hv = h4[i];
      d0 = dot2(w.x, hv.x, d0); d1 = dot2(w.y, hv.y, d1);
      d0 = dot2(w.z, hv.z, d0); d1 = dot2(w.w, hv.w, d1);
    }
#pragma unroll 8
    for (int i = 0; i < NPIN; ++i) {
      const uint4 w = Wlds[i * 512 + tid];
      const uint4 hv = h4[64 - NPIN + i];
      d0 = dot2(w.x, hv.x, d0); d1 = dot2(w.y, hv.y, d1);
      d0 = dot2(w.z, hv.z, d0); d1 = dot2(w.w, hv.w, d1);
    }

    // --- epilogue: tau, tanh, Euler update ---
    const float tau = 5.0f + 45.0f / (1.0f + __expf(-s));
    const float e2 = __expf(2.0f * (d0 + d1));
    const float drv = 1.0f - 2.0f / (e2 + 1.0f);       // tanh
    const float hnew = hold + (drv - hold) / tau;
    hold = hnew;
    hh[(t + 1) & 1][tid] = f16b(hnew);
    ((char*)Hq)[tid] = (char)(__float2int_rn(hnew * 127.f) & 255);
    xprow[tid] = hnew;                                 // hs output (dead xp slot)
    __syncthreads();                                   // sync3

    xprow += Hsz;
    Urow  += KH;
  }
}

// ---------------------------------------------------------------------------
// Epilogue: out[m,o] = hs[m,:] @ W_out[:,o] + b_out[o]
// ---------------------------------------------------------------------------
__global__ __launch_bounds__(256) void outproj_kernel(
    const float* __restrict__ hs, const float* __restrict__ W_out,
    const float* __restrict__ b_out, float* __restrict__ out)
{
  const int m = blockIdx.x * 16 + (threadIdx.x >> 4);
  const int o = threadIdx.x & 15;
  if (o >= Osz) return;
  const float* hrow = hs + (size_t)m * Hsz;
  float acc = b_out[o];
#pragma unroll 8
  for (int kk = 0; kk < Hsz; ++kk)
    acc = fmaf(hrow[kk], W_out[(size_t)kk * Osz + o], acc);
  out[(size_t)m * Osz + o] = acc;
}

// ---------------------------------------------------------------------------
extern "C" void kernel_launch(void* const* d_in, const int* in_sizes, int n_in,
                              void* d_out, int out_size, void* d_ws, size_t ws_size,
                              hipStream_t stream) {
  (void)in_sizes; (void)n_in; (void)out_size; (void)ws_size;

  const float* x      = (const float*)d_in[0];
  const float* W_in   = (const float*)d_in[1];
  const float* b_in   = (const float*)d_in[2];
  const float* W_rec  = (const float*)d_in[3];
  const float* bias   = (const float*)d_in[4];
  const float* W_tau1 = (const float*)d_in[5];
  const float* b_tau1 = (const float*)d_in[6];
  const float* W_tau2 = (const float*)d_in[7];
  const float* b_tau2 = (const float*)d_in[8];
  const float* W_out  = (const float*)d_in[9];
  const float* b_out  = (const float*)d_in[10];
  float* out = (float*)d_out;

  char* ws = (char*)d_ws;
  size_t off = 0;
  float* xps = (float*)(ws + off); off += (size_t)Bsz * Tsz * Hsz * 4;  // 128 MiB
  float* U   = (float*)(ws + off); off += (size_t)Bsz * Tsz * KH * 4;   //  64 MiB
  unsigned* P0 = (unsigned*)(ws + off); off += (size_t)256 * Hsz * 4;   // 512 KiB
  unsigned* Q1 = (unsigned*)(ws + off); off += (size_t)32 * 256 * 4 * 4;// 128 KiB
  unsigned* Q2 = (unsigned*)(ws + off); off += (size_t)16 * Hsz * 4 * 4;// 128 KiB
  float* CS1   = (float*)(ws + off); off += 256 * 4;
  float* CS2   = (float*)(ws + off); off += 512 * 4;

  const float* W1b = W_tau1 + (size_t)Hsz * KH;  // rows 512..1023

  const int M = Bsz * Tsz;  // 65536

  // opt-in to >64KB dynamic LDS for the scan kernel (idempotent, host-side)
  static_assert(NPIN * 512 * sizeof(uint4) == 131072, "dyn LDS size");
  (void)hipFuncSetAttribute((const void*)scan_kernel,
                            hipFuncAttributeMaxDynamicSharedMemorySize, 131072);

  // weight repack
  pack_p0_kernel<<<(256 * Hsz + 255) / 256, 256, 0, stream>>>(W_rec, P0);
  tau1_scale_kernel<<<1, 256, 0, stream>>>(W1b, CS1);
  tau1_quant_kernel<<<128, 256, 0, stream>>>(W1b, CS1, Q1);
  tau2_scale_kernel<<<2, 256, 0, stream>>>(W_tau2, CS2);
  tau2_quant_kernel<<<128, 256, 0, stream>>>(W_tau2, CS2, Q2);

  // xp = x @ W_in + b_in
  {
    dim3 grid(M / 64, Hsz / 64);
    gemm_bias_kernel<<<grid, 256, 0, stream>>>(x, W_in, b_in, xps, M, Hsz, Isz);
  }
  // U = xp @ W_tau1[:512] + b_tau1
  {
    dim3 grid(M / 64, KH / 64);
    gemm_bias_kernel<<<grid, 256, 0, stream>>>(xps, W_tau1, b_tau1, U, M, KH, Hsz);
  }
  // scan (64 WGs, one per batch element; 128 KB dynamic LDS)
  scan_kernel<<<Bsz, 512, 131072, stream>>>(xps, U, P0, Q1, Q2, CS1, CS2,
                                            bias, b_tau2);
  // output projection
  outproj_kernel<<<M / 16, 256, 0, stream>>>(xps, W_out, b_out, out);
}

// Round 10
// 6832.726 us; speedup vs baseline: 4.1738x; 1.0381x over previous
//
#include <hip/hip_runtime.h>
#include <hip/hip_fp16.h>
#include <math.h>

#define Bsz 64
#define Tsz 1024
#define Isz 128
#define Hsz 512
#define KH  256   // H/2
#define Osz 10

// ---------------------------------------------------------------------------
// Register-tiled fp32 GEMM: C[M,N] = A[M,K] @ Bw[K,N] + bias[N]
// ---------------------------------------------------------------------------
__global__ __launch_bounds__(256) void gemm_bias_kernel(
    const float* __restrict__ A, const float* __restrict__ Bw,
    const float* __restrict__ bias, float* __restrict__ C,
    int M, int N, int K)
{
  __shared__ float As[32][65];
  const int tid = threadIdx.x;
  const int m0 = blockIdx.x * 64;
  const int n0 = blockIdx.y * 64;
  const int ty = tid >> 4, tx = tid & 15;

  float acc[4][4] = {{0.f}};

  for (int kk = 0; kk < K; kk += 32) {
    __syncthreads();
#pragma unroll
    for (int i = tid; i < 64 * 32; i += 256) {
      int m = i >> 5, k = i & 31;
      As[k][m] = A[(size_t)(m0 + m) * K + kk + k];
    }
    __syncthreads();
#pragma unroll
    for (int k = 0; k < 32; ++k) {
      float a0 = As[k][ty * 4 + 0];
      float a1 = As[k][ty * 4 + 1];
      float a2 = As[k][ty * 4 + 2];
      float a3 = As[k][ty * 4 + 3];
      const float4 bv = *(const float4*)(&Bw[(size_t)(kk + k) * N + n0 + tx * 4]);
      acc[0][0] += a0 * bv.x; acc[0][1] += a0 * bv.y; acc[0][2] += a0 * bv.z; acc[0][3] += a0 * bv.w;
      acc[1][0] += a1 * bv.x; acc[1][1] += a1 * bv.y; acc[1][2] += a1 * bv.z; acc[1][3] += a1 * bv.w;
      acc[2][0] += a2 * bv.x; acc[2][1] += a2 * bv.y; acc[2][2] += a2 * bv.z; acc[2][3] += a2 * bv.w;
      acc[3][0] += a3 * bv.x; acc[3][1] += a3 * bv.y; acc[3][2] += a3 * bv.z; acc[3][3] += a3 * bv.w;
    }
  }

  const float4 bb = *(const float4*)(&bias[n0 + tx * 4]);
#pragma unroll
  for (int i = 0; i < 4; ++i) {
    float4 v;
    v.x = acc[i][0] + bb.x; v.y = acc[i][1] + bb.y;
    v.z = acc[i][2] + bb.z; v.w = acc[i][3] + bb.w;
    *(float4*)(&C[(size_t)(m0 + ty * 4 + i) * N + n0 + tx * 4]) = v;
  }
}

// ---------------------------------------------------------------------------
// i8 dot4
// ---------------------------------------------------------------------------
__device__ __forceinline__ int dot4i8(int a, int b, int acc) {
#if __has_builtin(__builtin_amdgcn_sdot4)
  return __builtin_amdgcn_sdot4(a, b, acc, false);
#else
  acc += ((a << 24) >> 24) * ((b << 24) >> 24);
  acc += ((a << 16) >> 24) * ((b << 16) >> 24);
  acc += ((a << 8)  >> 24) * ((b << 8)  >> 24);
  acc += (a >> 24) * (b >> 24);
  return acc;
#endif
}

// ---------------------------------------------------------------------------
// Quantizer layouts: a [G groups x C cols] i8 matrix where group g, dword di,
// byte e covers source k = 16g + 4di + e; flat dword index = g*(C*4)+c*4+di.
// Each streamed load is a per-thread uint4 (4 dwords = 16 k-elements).
// ---------------------------------------------------------------------------

// drive: col j = output row of W_rec (512 cols, 32 groups over k=512)
__global__ __launch_bounds__(256) void drive_scale_kernel(
    const float* __restrict__ W_rec, float* __restrict__ CS0)
{
  const int j = blockIdx.x * 256 + threadIdx.x;  // 512
  float m = 0.f;
  for (int k = 0; k < Hsz; ++k)
    m = fmaxf(m, fabsf(W_rec[(size_t)j * Hsz + k]));
  CS0[j] = m;
}

__global__ __launch_bounds__(256) void drive_quant_kernel(
    const float* __restrict__ W_rec, const float* __restrict__ CS0,
    unsigned* __restrict__ Q0)
{
  int i = blockIdx.x * 256 + threadIdx.x;  // 65536 dwords
  if (i >= 32 * Hsz * 4) return;
  int di = i & 3, j = (i >> 2) & 511, g = i >> 11;
  int k0 = 16 * g + 4 * di;
  float ma = CS0[j];
  float r = (ma > 0.f) ? (127.f / ma) : 0.f;
  unsigned out = 0;
#pragma unroll
  for (int e = 0; e < 4; ++e) {
    int q = __float2int_rn(W_rec[(size_t)j * Hsz + k0 + e] * r);
    out |= ((unsigned)(q & 255)) << (8 * e);
  }
  Q0[i] = out;
}

// tau1: col c (256 cols), 32 groups over j=512 (source W1b[j][c])
__global__ __launch_bounds__(256) void tau1_scale_kernel(
    const float* __restrict__ W1b, float* __restrict__ CS1)
{
  const int c = threadIdx.x;  // 256
  float m = 0.f;
  for (int j = 0; j < Hsz; ++j)
    m = fmaxf(m, fabsf(W1b[(size_t)j * KH + c]));
  CS1[c] = m;
}

__global__ __launch_bounds__(256) void tau1_quant_kernel(
    const float* __restrict__ W1b, const float* __restrict__ CS1,
    unsigned* __restrict__ Q1)
{
  int i = blockIdx.x * 256 + threadIdx.x;  // 32768 dwords
  if (i >= 32 * KH * 4) return;
  int di = i & 3, c = (i >> 2) & 255, g = i >> 10;
  int j0 = 16 * g + 4 * di;
  float ma = CS1[c];
  float r = (ma > 0.f) ? (127.f / ma) : 0.f;
  unsigned out = 0;
#pragma unroll
  for (int e = 0; e < 4; ++e) {
    int q = __float2int_rn(W1b[(size_t)(j0 + e) * KH + c] * r);
    out |= ((unsigned)(q & 255)) << (8 * e);
  }
  Q1[i] = out;
}

// tau2: col j (512 cols), 16 groups over k=256 (source W_tau2[k][j])
__global__ __launch_bounds__(256) void tau2_scale_kernel(
    const float* __restrict__ W_tau2, float* __restrict__ CS2)
{
  const int j = blockIdx.x * 256 + threadIdx.x;  // 512
  float m = 0.f;
  for (int k = 0; k < KH; ++k)
    m = fmaxf(m, fabsf(W_tau2[(size_t)k * Hsz + j]));
  CS2[j] = m;
}

__global__ __launch_bounds__(256) void tau2_quant_kernel(
    const float* __restrict__ W_tau2, const float* __restrict__ CS2,
    unsigned* __restrict__ Q2)
{
  int i = blockIdx.x * 256 + threadIdx.x;  // 32768 dwords
  if (i >= 16 * Hsz * 4) return;
  int di = i & 3, j = (i >> 2) & 511, g = i >> 11;
  int k0 = 16 * g + 4 * di;
  float ma = CS2[j];
  float r = (ma > 0.f) ? (127.f / ma) : 0.f;
  unsigned out = 0;
#pragma unroll
  for (int e = 0; e < 4; ++e) {
    int q = __float2int_rn(W_tau2[(size_t)(k0 + e) * Hsz + j] * r);
    out |= ((unsigned)(q & 255)) << (8 * e);
  }
  Q2[i] = out;
}

// ---------------------------------------------------------------------------
// Sequential scan. One WG (512 threads) per batch element. ALL three matvecs
// in i8 (per-column weight scales; h exchanged as i8 x127 with f32 'hold'
// kept in-register for the Euler update; A quantized per-64-lane-wave scale,
// no extra barrier). Drive: 16 of 32 i8 groups pinned in 128 KB dynamic LDS.
// Streamed/thread/step: 256(drive) + 256(tau1) + 256(tau2) = 768 B.
// 3 barriers/step. Unroll 8 on streamed loops (R8 lesson: 8 in-flight loads).
// ---------------------------------------------------------------------------
__global__ __launch_bounds__(512) void scan_kernel(
    float* __restrict__ xps,           // in: xp [B,T,H]; out: hs [B,T,H]
    const float* __restrict__ U,       // [B,T,KH] (b_tau1 already added)
    const unsigned* __restrict__ Q0,   // i8 drive [32][512][4]
    const unsigned* __restrict__ Q1,   // i8 tau1  [32][256][4]
    const unsigned* __restrict__ Q2,   // i8 tau2  [16][512][4]
    const float* __restrict__ CS0,     // [512]
    const float* __restrict__ CS1,     // [256]
    const float* __restrict__ CS2,     // [512]
    const float* __restrict__ bias,    // [H]
    const float* __restrict__ b_tau2)  // [H]
{
  const int b = blockIdx.x;
  const int tid = threadIdx.x;
  const int hs = tid >> 8;             // tau1 k-half
  const int c  = tid & 255;            // tau1 column

  extern __shared__ __align__(16) uint4 Wlds[];  // 16*512 uint4 = 128 KB (drive groups 16..31)
  __shared__ __align__(16) int Hq[128];          // i8 h (512 B)
  __shared__ __align__(16) unsigned char Aq[KH]; // i8 A (256 B)
  __shared__ float scaleA[4];                    // per-wave A amax
  __shared__ int parti[2][KH];

  const float bias_r = bias[tid];
  const float bt2_r  = b_tau2[tid];
  const float cs0r = CS0[tid] * (1.0f / 16129.0f);  // /127^2
  const float csr  = CS1[c]   * (1.0f / 16129.0f);
  const float cs2r = CS2[tid] * (1.0f / 16129.0f);
  float hold = 0.f;
  if (tid < 128) Hq[tid] = 0;

  float* xprow = xps + (size_t)b * Tsz * Hsz;
  const float* Urow = U + (size_t)b * Tsz * KH;

  const uint4* __restrict__ q0 = (const uint4*)Q0 + tid;                 // stride 512
  const uint4* __restrict__ q1 = (const uint4*)Q1 + (size_t)(hs * 16) * 256 + c; // stride 256
  const uint4* __restrict__ q2 = (const uint4*)Q2 + tid;                 // stride 512
  const uint4* Hq4 = (const uint4*)Hq;
  const uint4* Aq4 = (const uint4*)Aq;

  // --- one-time: stage drive groups 16..31 (k=256..511) into dynamic LDS ---
#pragma unroll
  for (int i = 0; i < 16; ++i)
    Wlds[i * 512 + tid] = q0[(size_t)(16 + i) * 512];

  __syncthreads();

  for (int t = 0; t < Tsz; ++t) {
    const float xpv = xprow[tid];
    const float Uv = (tid < KH) ? Urow[tid] : 0.f;

    // --- drive (i8): 16 streamed groups + 16 LDS groups ---
    int d0i = 0, d1i = 0;
#pragma unroll 8
    for (int g = 0; g < 16; ++g) {
      const uint4 w  = q0[(size_t)g * 512];
      const uint4 hv = Hq4[g];
      d0i = dot4i8((int)w.x, (int)hv.x, d0i); d1i = dot4i8((int)w.y, (int)hv.y, d1i);
      d0i = dot4i8((int)w.z, (int)hv.z, d0i); d1i = dot4i8((int)w.w, (int)hv.w, d1i);
    }
#pragma unroll 8
    for (int g = 0; g < 16; ++g) {
      const uint4 w  = Wlds[g * 512 + tid];
      const uint4 hv = Hq4[16 + g];
      d0i = dot4i8((int)w.x, (int)hv.x, d0i); d1i = dot4i8((int)w.y, (int)hv.y, d1i);
      d0i = dot4i8((int)w.z, (int)hv.z, d0i); d1i = dot4i8((int)w.w, (int)hv.w, d1i);
    }

    // --- tau1 partial (i8): this thread's 256-element k-half of column c ---
    int a0 = 0, a1 = 0;
#pragma unroll 8
    for (int g = 0; g < 16; ++g) {
      const uint4 w  = q1[(size_t)g * 256];
      const uint4 hv = Hq4[hs * 16 + g];
      a0 = dot4i8((int)w.x, (int)hv.x, a0); a1 = dot4i8((int)w.y, (int)hv.y, a1);
      a0 = dot4i8((int)w.z, (int)hv.z, a0); a1 = dot4i8((int)w.w, (int)hv.w, a1);
    }
    parti[hs][c] = a0 + a1;
    __syncthreads();                                   // sync1

    // --- A + per-wave (64-lane segment) quantization, no extra barrier ---
    if (tid < KH) {
      float aval = fmaxf(Uv + (float)(parti[0][tid] + parti[1][tid]) * csr, 0.f);
      float m = aval;
#pragma unroll
      for (int off = 32; off >= 1; off >>= 1)
        m = fmaxf(m, __shfl_xor(m, off));              // amax over the wave's 64 A vals
      if ((tid & 63) == 0) scaleA[tid >> 6] = m;
      const float r = (m > 0.f) ? (127.f / m) : 0.f;
      Aq[tid] = (unsigned char)__float2int_rn(aval * r);
    }
    __syncthreads();                                   // sync2

    // --- tau2 (i8): 4 k-segments, each with its own A scale ---
    float s = bt2_r;
#pragma unroll
    for (int q = 0; q < 4; ++q) {
      int s0i = 0, s1i = 0;
#pragma unroll
      for (int g = 4 * q; g < 4 * q + 4; ++g) {
        const uint4 w  = q2[(size_t)g * 512];
        const uint4 av = Aq4[g];
        s0i = dot4i8((int)w.x, (int)av.x, s0i); s1i = dot4i8((int)w.y, (int)av.y, s1i);
        s0i = dot4i8((int)w.z, (int)av.z, s0i); s1i = dot4i8((int)w.w, (int)av.w, s1i);
      }
      s += (float)(s0i + s1i) * cs2r * scaleA[q];
    }

    // --- epilogue: tau, tanh, Euler update ---
    const float d = xpv + bias_r + (float)(d0i + d1i) * cs0r;
    const float tau = 5.0f + 45.0f / (1.0f + __expf(-s));
    const float e2 = __expf(2.0f * d);
    const float drv = 1.0f - 2.0f / (e2 + 1.0f);       // tanh
    const float hnew = hold + (drv - hold) / tau;
    hold = hnew;
    ((char*)Hq)[tid] = (char)(__float2int_rn(hnew * 127.f) & 255);
    xprow[tid] = hnew;                                 // hs output (dead xp slot)
    __syncthreads();                                   // sync3

    xprow += Hsz;
    Urow  += KH;
  }
}

// ---------------------------------------------------------------------------
// Epilogue: out[m,o] = hs[m,:] @ W_out[:,o] + b_out[o]
// ---------------------------------------------------------------------------
__global__ __launch_bounds__(256) void outproj_kernel(
    const float* __restrict__ hs, const float* __restrict__ W_out,
    const float* __restrict__ b_out, float* __restrict__ out)
{
  const int m = blockIdx.x * 16 + (threadIdx.x >> 4);
  const int o = threadIdx.x & 15;
  if (o >= Osz) return;
  const float* hrow = hs + (size_t)m * Hsz;
  float acc = b_out[o];
#pragma unroll 8
  for (int kk = 0; kk < Hsz; ++kk)
    acc = fmaf(hrow[kk], W_out[(size_t)kk * Osz + o], acc);
  out[(size_t)m * Osz + o] = acc;
}

// ---------------------------------------------------------------------------
extern "C" void kernel_launch(void* const* d_in, const int* in_sizes, int n_in,
                              void* d_out, int out_size, void* d_ws, size_t ws_size,
                              hipStream_t stream) {
  (void)in_sizes; (void)n_in; (void)out_size; (void)ws_size;

  const float* x      = (const float*)d_in[0];
  const float* W_in   = (const float*)d_in[1];
  const float* b_in   = (const float*)d_in[2];
  const float* W_rec  = (const float*)d_in[3];
  const float* bias   = (const float*)d_in[4];
  const float* W_tau1 = (const float*)d_in[5];
  const float* b_tau1 = (const float*)d_in[6];
  const float* W_tau2 = (const float*)d_in[7];
  const float* b_tau2 = (const float*)d_in[8];
  const float* W_out  = (const float*)d_in[9];
  const float* b_out  = (const float*)d_in[10];
  float* out = (float*)d_out;

  char* ws = (char*)d_ws;
  size_t off = 0;
  float* xps = (float*)(ws + off); off += (size_t)Bsz * Tsz * Hsz * 4;  // 128 MiB
  float* U   = (float*)(ws + off); off += (size_t)Bsz * Tsz * KH * 4;   //  64 MiB
  unsigned* Q0 = (unsigned*)(ws + off); off += (size_t)32 * Hsz * 4 * 4;// 256 KiB
  unsigned* Q1 = (unsigned*)(ws + off); off += (size_t)32 * KH  * 4 * 4;// 128 KiB
  unsigned* Q2 = (unsigned*)(ws + off); off += (size_t)16 * Hsz * 4 * 4;// 128 KiB
  float* CS0   = (float*)(ws + off); off += 512 * 4;
  float* CS1   = (float*)(ws + off); off += 256 * 4;
  float* CS2   = (float*)(ws + off); off += 512 * 4;

  const float* W1b = W_tau1 + (size_t)Hsz * KH;  // rows 512..1023

  const int M = Bsz * Tsz;  // 65536

  // opt-in to 128 KB dynamic LDS for the scan kernel
  (void)hipFuncSetAttribute((const void*)scan_kernel,
                            hipFuncAttributeMaxDynamicSharedMemorySize, 131072);

  // weight quantization
  drive_scale_kernel<<<2, 256, 0, stream>>>(W_rec, CS0);
  drive_quant_kernel<<<256, 256, 0, stream>>>(W_rec, CS0, Q0);
  tau1_scale_kernel<<<1, 256, 0, stream>>>(W1b, CS1);
  tau1_quant_kernel<<<128, 256, 0, stream>>>(W1b, CS1, Q1);
  tau2_scale_kernel<<<2, 256, 0, stream>>>(W_tau2, CS2);
  tau2_quant_kernel<<<128, 256, 0, stream>>>(W_tau2, CS2, Q2);

  // xp = x @ W_in + b_in
  {
    dim3 grid(M / 64, Hsz / 64);
    gemm_bias_kernel<<<grid, 256, 0, stream>>>(x, W_in, b_in, xps, M, Hsz, Isz);
  }
  // U = xp @ W_tau1[:512] + b_tau1
  {
    dim3 grid(M / 64, KH / 64);
    gemm_bias_kernel<<<grid, 256, 0, stream>>>(xps, W_tau1, b_tau1, U, M, KH, Hsz);
  }
  // scan (64 WGs, one per batch element; 128 KB dynamic LDS)
  scan_kernel<<<Bsz, 512, 131072, stream>>>(xps, U, Q0, Q1, Q2,
                                            CS0, CS1, CS2, bias, b_tau2);
  // output projection
  outproj_kernel<<<M / 16, 256, 0, stream>>>(xps, W_out, b_out, out);
}

// Round 11
// 5387.161 us; speedup vs baseline: 5.2938x; 1.2683x over previous
//
#include <hip/hip_runtime.h>
#include <hip/hip_fp16.h>
#include <math.h>

#define Bsz 64
#define Tsz 1024
#define Isz 128
#define Hsz 512
#define KH  256   // H/2
#define Osz 10

// ---------------------------------------------------------------------------
// Register-tiled fp32 GEMM: C[M,N] = A[M,K] @ Bw[K,N] + bias[N]
// ---------------------------------------------------------------------------
__global__ __launch_bounds__(256) void gemm_bias_kernel(
    const float* __restrict__ A, const float* __restrict__ Bw,
    const float* __restrict__ bias, float* __restrict__ C,
    int M, int N, int K)
{
  __shared__ float As[32][65];
  const int tid = threadIdx.x;
  const int m0 = blockIdx.x * 64;
  const int n0 = blockIdx.y * 64;
  const int ty = tid >> 4, tx = tid & 15;

  float acc[4][4] = {{0.f}};

  for (int kk = 0; kk < K; kk += 32) {
    __syncthreads();
#pragma unroll
    for (int i = tid; i < 64 * 32; i += 256) {
      int m = i >> 5, k = i & 31;
      As[k][m] = A[(size_t)(m0 + m) * K + kk + k];
    }
    __syncthreads();
#pragma unroll
    for (int k = 0; k < 32; ++k) {
      float a0 = As[k][ty * 4 + 0];
      float a1 = As[k][ty * 4 + 1];
      float a2 = As[k][ty * 4 + 2];
      float a3 = As[k][ty * 4 + 3];
      const float4 bv = *(const float4*)(&Bw[(size_t)(kk + k) * N + n0 + tx * 4]);
      acc[0][0] += a0 * bv.x; acc[0][1] += a0 * bv.y; acc[0][2] += a0 * bv.z; acc[0][3] += a0 * bv.w;
      acc[1][0] += a1 * bv.x; acc[1][1] += a1 * bv.y; acc[1][2] += a1 * bv.z; acc[1][3] += a1 * bv.w;
      acc[2][0] += a2 * bv.x; acc[2][1] += a2 * bv.y; acc[2][2] += a2 * bv.z; acc[2][3] += a2 * bv.w;
      acc[3][0] += a3 * bv.x; acc[3][1] += a3 * bv.y; acc[3][2] += a3 * bv.z; acc[3][3] += a3 * bv.w;
    }
  }

  const float4 bb = *(const float4*)(&bias[n0 + tx * 4]);
#pragma unroll
  for (int i = 0; i < 4; ++i) {
    float4 v;
    v.x = acc[i][0] + bb.x; v.y = acc[i][1] + bb.y;
    v.z = acc[i][2] + bb.z; v.w = acc[i][3] + bb.w;
    *(float4*)(&C[(size_t)(m0 + ty * 4 + i) * N + n0 + tx * 4]) = v;
  }
}

// ---------------------------------------------------------------------------
// i8 dot4
// ---------------------------------------------------------------------------
__device__ __forceinline__ int dot4i8(int a, int b, int acc) {
#if __has_builtin(__builtin_amdgcn_sdot4)
  return __builtin_amdgcn_sdot4(a, b, acc, false);
#else
  acc += ((a << 24) >> 24) * ((b << 24) >> 24);
  acc += ((a << 16) >> 24) * ((b << 16) >> 24);
  acc += ((a << 8)  >> 24) * ((b << 8)  >> 24);
  acc += (a >> 24) * (b >> 24);
  return acc;
#endif
}

// ---------------------------------------------------------------------------
// Quantizer layouts: a [G groups x C cols] i8 matrix where group g, dword di,
// byte e covers source k = 16g + 4di + e; flat dword index = g*(C*4)+c*4+di.
// Each streamed load is a per-thread uint4 (4 dwords = 16 k-elements).
// ---------------------------------------------------------------------------

// drive: col j = output row of W_rec (512 cols, 32 groups over k=512)
__global__ __launch_bounds__(256) void drive_scale_kernel(
    const float* __restrict__ W_rec, float* __restrict__ CS0)
{
  const int j = blockIdx.x * 256 + threadIdx.x;  // 512
  float m = 0.f;
  for (int k = 0; k < Hsz; ++k)
    m = fmaxf(m, fabsf(W_rec[(size_t)j * Hsz + k]));
  CS0[j] = m;
}

__global__ __launch_bounds__(256) void drive_quant_kernel(
    const float* __restrict__ W_rec, const float* __restrict__ CS0,
    unsigned* __restrict__ Q0)
{
  int i = blockIdx.x * 256 + threadIdx.x;  // 65536 dwords
  if (i >= 32 * Hsz * 4) return;
  int di = i & 3, j = (i >> 2) & 511, g = i >> 11;
  int k0 = 16 * g + 4 * di;
  float ma = CS0[j];
  float r = (ma > 0.f) ? (127.f / ma) : 0.f;
  unsigned out = 0;
#pragma unroll
  for (int e = 0; e < 4; ++e) {
    int q = __float2int_rn(W_rec[(size_t)j * Hsz + k0 + e] * r);
    out |= ((unsigned)(q & 255)) << (8 * e);
  }
  Q0[i] = out;
}

// tau1: col c (256 cols), 32 groups over j=512 (source W1b[j][c])
__global__ __launch_bounds__(256) void tau1_scale_kernel(
    const float* __restrict__ W1b, float* __restrict__ CS1)
{
  const int c = threadIdx.x;  // 256
  float m = 0.f;
  for (int j = 0; j < Hsz; ++j)
    m = fmaxf(m, fabsf(W1b[(size_t)j * KH + c]));
  CS1[c] = m;
}

__global__ __launch_bounds__(256) void tau1_quant_kernel(
    const float* __restrict__ W1b, const float* __restrict__ CS1,
    unsigned* __restrict__ Q1)
{
  int i = blockIdx.x * 256 + threadIdx.x;  // 32768 dwords
  if (i >= 32 * KH * 4) return;
  int di = i & 3, c = (i >> 2) & 255, g = i >> 10;
  int j0 = 16 * g + 4 * di;
  float ma = CS1[c];
  float r = (ma > 0.f) ? (127.f / ma) : 0.f;
  unsigned out = 0;
#pragma unroll
  for (int e = 0; e < 4; ++e) {
    int q = __float2int_rn(W1b[(size_t)(j0 + e) * KH + c] * r);
    out |= ((unsigned)(q & 255)) << (8 * e);
  }
  Q1[i] = out;
}

// tau2: col j (512 cols), 16 groups over k=256 (source W_tau2[k][j])
__global__ __launch_bounds__(256) void tau2_scale_kernel(
    const float* __restrict__ W_tau2, float* __restrict__ CS2)
{
  const int j = blockIdx.x * 256 + threadIdx.x;  // 512
  float m = 0.f;
  for (int k = 0; k < KH; ++k)
    m = fmaxf(m, fabsf(W_tau2[(size_t)k * Hsz + j]));
  CS2[j] = m;
}

__global__ __launch_bounds__(256) void tau2_quant_kernel(
    const float* __restrict__ W_tau2, const float* __restrict__ CS2,
    unsigned* __restrict__ Q2)
{
  int i = blockIdx.x * 256 + threadIdx.x;  // 32768 dwords
  if (i >= 16 * Hsz * 4) return;
  int di = i & 3, j = (i >> 2) & 511, g = i >> 11;
  int k0 = 16 * g + 4 * di;
  float ma = CS2[j];
  float r = (ma > 0.f) ? (127.f / ma) : 0.f;
  unsigned out = 0;
#pragma unroll
  for (int e = 0; e < 4; ++e) {
    int q = __float2int_rn(W_tau2[(size_t)(k0 + e) * Hsz + j] * r);
    out |= ((unsigned)(q & 255)) << (8 * e);
  }
  Q2[i] = out;
}

// ---------------------------------------------------------------------------
// Sequential scan. One WG (512 threads) per batch element. All matvecs i8.
// LDS pin (144 KB dynamic) re-targeted vs R10: ALL 16 tau2 groups (128 KB)
// + drive groups 30,31 (16 KB). This makes the post-sync2 tau2 phase
// global-load-free and concentrates ALL streaming (30 drive + 16 tau1
// groups, 736 B/thread/step) in the single long pre-sync1 phase -> one L2
// ramp per step instead of two, max loads in flight.
// 3 barriers/step.
// ---------------------------------------------------------------------------
__global__ __launch_bounds__(512) void scan_kernel(
    float* __restrict__ xps,           // in: xp [B,T,H]; out: hs [B,T,H]
    const float* __restrict__ U,       // [B,T,KH] (b_tau1 already added)
    const unsigned* __restrict__ Q0,   // i8 drive [32][512][4]
    const unsigned* __restrict__ Q1,   // i8 tau1  [32][256][4]
    const unsigned* __restrict__ Q2,   // i8 tau2  [16][512][4]
    const float* __restrict__ CS0,     // [512]
    const float* __restrict__ CS1,     // [256]
    const float* __restrict__ CS2,     // [512]
    const float* __restrict__ bias,    // [H]
    const float* __restrict__ b_tau2)  // [H]
{
  const int b = blockIdx.x;
  const int tid = threadIdx.x;
  const int hs = tid >> 8;             // tau1 k-half
  const int c  = tid & 255;            // tau1 column

  // dynamic LDS: [0..8191] = tau2 groups 0..15; [8192..9215] = drive g30,g31
  extern __shared__ __align__(16) uint4 Wlds[];
  __shared__ __align__(16) int Hq[128];          // i8 h (512 B)
  __shared__ __align__(16) unsigned char Aq[KH]; // i8 A (256 B)
  __shared__ float scaleA[4];                    // per-wave A amax
  __shared__ int parti[2][KH];

  const float bias_r = bias[tid];
  const float bt2_r  = b_tau2[tid];
  const float cs0r = CS0[tid] * (1.0f / 16129.0f);  // /127^2
  const float csr  = CS1[c]   * (1.0f / 16129.0f);
  const float cs2r = CS2[tid] * (1.0f / 16129.0f);
  float hold = 0.f;
  if (tid < 128) Hq[tid] = 0;

  float* xprow = xps + (size_t)b * Tsz * Hsz;
  const float* Urow = U + (size_t)b * Tsz * KH;

  const uint4* __restrict__ q0 = (const uint4*)Q0 + tid;                 // stride 512
  const uint4* __restrict__ q1 = (const uint4*)Q1 + (size_t)(hs * 16) * 256 + c; // stride 256
  const uint4* __restrict__ q2 = (const uint4*)Q2 + tid;                 // stride 512
  const uint4* Hq4 = (const uint4*)Hq;
  const uint4* Aq4 = (const uint4*)Aq;

  // --- one-time LDS staging: 16 tau2 groups + drive groups 30,31 ---
#pragma unroll
  for (int i = 0; i < 16; ++i)
    Wlds[i * 512 + tid] = q2[(size_t)i * 512];
#pragma unroll
  for (int i = 0; i < 2; ++i)
    Wlds[8192 + i * 512 + tid] = q0[(size_t)(30 + i) * 512];

  __syncthreads();

  for (int t = 0; t < Tsz; ++t) {
    const float xpv = xprow[tid];
    const float Uv = (tid < KH) ? Urow[tid] : 0.f;

    // --- drive (i8): 30 streamed groups + 2 LDS groups ---
    int d0i = 0, d1i = 0;
#pragma unroll 8
    for (int g = 0; g < 30; ++g) {
      const uint4 w  = q0[(size_t)g * 512];
      const uint4 hv = Hq4[g];
      d0i = dot4i8((int)w.x, (int)hv.x, d0i); d1i = dot4i8((int)w.y, (int)hv.y, d1i);
      d0i = dot4i8((int)w.z, (int)hv.z, d0i); d1i = dot4i8((int)w.w, (int)hv.w, d1i);
    }
#pragma unroll
    for (int g = 0; g < 2; ++g) {
      const uint4 w  = Wlds[8192 + g * 512 + tid];
      const uint4 hv = Hq4[30 + g];
      d0i = dot4i8((int)w.x, (int)hv.x, d0i); d1i = dot4i8((int)w.y, (int)hv.y, d1i);
      d0i = dot4i8((int)w.z, (int)hv.z, d0i); d1i = dot4i8((int)w.w, (int)hv.w, d1i);
    }

    // --- tau1 partial (i8): this thread's 256-element k-half of column c ---
    int a0 = 0, a1 = 0;
#pragma unroll 8
    for (int g = 0; g < 16; ++g) {
      const uint4 w  = q1[(size_t)g * 256];
      const uint4 hv = Hq4[hs * 16 + g];
      a0 = dot4i8((int)w.x, (int)hv.x, a0); a1 = dot4i8((int)w.y, (int)hv.y, a1);
      a0 = dot4i8((int)w.z, (int)hv.z, a0); a1 = dot4i8((int)w.w, (int)hv.w, a1);
    }
    parti[hs][c] = a0 + a1;
    __syncthreads();                                   // sync1

    // --- A + per-wave (64-lane segment) quantization ---
    if (tid < KH) {
      float aval = fmaxf(Uv + (float)(parti[0][tid] + parti[1][tid]) * csr, 0.f);
      float m = aval;
#pragma unroll
      for (int off = 32; off >= 1; off >>= 1)
        m = fmaxf(m, __shfl_xor(m, off));              // amax over the wave's 64 A vals
      if ((tid & 63) == 0) scaleA[tid >> 6] = m;
      const float r = (m > 0.f) ? (127.f / m) : 0.f;
      Aq[tid] = (unsigned char)__float2int_rn(aval * r);
    }
    __syncthreads();                                   // sync2

    // --- tau2 (i8): ALL 16 groups from LDS, 4 k-segments w/ per-wave scale ---
    float s = bt2_r;
#pragma unroll
    for (int q = 0; q < 4; ++q) {
      int s0i = 0, s1i = 0;
#pragma unroll
      for (int g = 4 * q; g < 4 * q + 4; ++g) {
        const uint4 w  = Wlds[g * 512 + tid];
        const uint4 av = Aq4[g];
        s0i = dot4i8((int)w.x, (int)av.x, s0i); s1i = dot4i8((int)w.y, (int)av.y, s1i);
        s0i = dot4i8((int)w.z, (int)av.z, s0i); s1i = dot4i8((int)w.w, (int)av.w, s1i);
      }
      s += (float)(s0i + s1i) * cs2r * scaleA[q];
    }

    // --- epilogue: tau, tanh, Euler update ---
    const float d = xpv + bias_r + (float)(d0i + d1i) * cs0r;
    const float tau = 5.0f + 45.0f / (1.0f + __expf(-s));
    const float e2 = __expf(2.0f * d);
    const float drv = 1.0f - 2.0f / (e2 + 1.0f);       // tanh
    const float hnew = hold + (drv - hold) / tau;
    hold = hnew;
    ((char*)Hq)[tid] = (char)(__float2int_rn(hnew * 127.f) & 255);
    xprow[tid] = hnew;                                 // hs output (dead xp slot)
    __syncthreads();                                   // sync3

    xprow += Hsz;
    Urow  += KH;
  }
}

// ---------------------------------------------------------------------------
// Epilogue: out[m,o] = hs[m,:] @ W_out[:,o] + b_out[o]
// ---------------------------------------------------------------------------
__global__ __launch_bounds__(256) void outproj_kernel(
    const float* __restrict__ hs, const float* __restrict__ W_out,
    const float* __restrict__ b_out, float* __restrict__ out)
{
  const int m = blockIdx.x * 16 + (threadIdx.x >> 4);
  const int o = threadIdx.x & 15;
  if (o >= Osz) return;
  const float* hrow = hs + (size_t)m * Hsz;
  float acc = b_out[o];
#pragma unroll 8
  for (int kk = 0; kk < Hsz; ++kk)
    acc = fmaf(hrow[kk], W_out[(size_t)kk * Osz + o], acc);
  out[(size_t)m * Osz + o] = acc;
}

// ---------------------------------------------------------------------------
extern "C" void kernel_launch(void* const* d_in, const int* in_sizes, int n_in,
                              void* d_out, int out_size, void* d_ws, size_t ws_size,
                              hipStream_t stream) {
  (void)in_sizes; (void)n_in; (void)out_size; (void)ws_size;

  const float* x      = (const float*)d_in[0];
  const float* W_in   = (const float*)d_in[1];
  const float* b_in   = (const float*)d_in[2];
  const float* W_rec  = (const float*)d_in[3];
  const float* bias   = (const float*)d_in[4];
  const float* W_tau1 = (const float*)d_in[5];
  const float* b_tau1 = (const float*)d_in[6];
  const float* W_tau2 = (const float*)d_in[7];
  const float* b_tau2 = (const float*)d_in[8];
  const float* W_out  = (const float*)d_in[9];
  const float* b_out  = (const float*)d_in[10];
  float* out = (float*)d_out;

  char* ws = (char*)d_ws;
  size_t off = 0;
  float* xps = (float*)(ws + off); off += (size_t)Bsz * Tsz * Hsz * 4;  // 128 MiB
  float* U   = (float*)(ws + off); off += (size_t)Bsz * Tsz * KH * 4;   //  64 MiB
  unsigned* Q0 = (unsigned*)(ws + off); off += (size_t)32 * Hsz * 4 * 4;// 256 KiB
  unsigned* Q1 = (unsigned*)(ws + off); off += (size_t)32 * KH  * 4 * 4;// 128 KiB
  unsigned* Q2 = (unsigned*)(ws + off); off += (size_t)16 * Hsz * 4 * 4;// 128 KiB
  float* CS0   = (float*)(ws + off); off += 512 * 4;
  float* CS1   = (float*)(ws + off); off += 256 * 4;
  float* CS2   = (float*)(ws + off); off += 512 * 4;

  const float* W1b = W_tau1 + (size_t)Hsz * KH;  // rows 512..1023

  const int M = Bsz * Tsz;  // 65536

  // opt-in to 144 KB dynamic LDS for the scan kernel
  (void)hipFuncSetAttribute((const void*)scan_kernel,
                            hipFuncAttributeMaxDynamicSharedMemorySize, 147456);

  // weight quantization
  drive_scale_kernel<<<2, 256, 0, stream>>>(W_rec, CS0);
  drive_quant_kernel<<<256, 256, 0, stream>>>(W_rec, CS0, Q0);
  tau1_scale_kernel<<<1, 256, 0, stream>>>(W1b, CS1);
  tau1_quant_kernel<<<128, 256, 0, stream>>>(W1b, CS1, Q1);
  tau2_scale_kernel<<<2, 256, 0, stream>>>(W_tau2, CS2);
  tau2_quant_kernel<<<128, 256, 0, stream>>>(W_tau2, CS2, Q2);

  // xp = x @ W_in + b_in
  {
    dim3 grid(M / 64, Hsz / 64);
    gemm_bias_kernel<<<grid, 256, 0, stream>>>(x, W_in, b_in, xps, M, Hsz, Isz);
  }
  // U = xp @ W_tau1[:512] + b_tau1
  {
    dim3 grid(M / 64, KH / 64);
    gemm_bias_kernel<<<grid, 256, 0, stream>>>(xps, W_tau1, b_tau1, U, M, KH, Hsz);
  }
  // scan (64 WGs, one per batch element; 144 KB dynamic LDS)
  scan_kernel<<<Bsz, 512, 147456, stream>>>(xps, U, Q0, Q1, Q2,
                                            CS0, CS1, CS2, bias, b_tau2);
  // output projection
  outproj_kernel<<<M / 16, 256, 0, stream>>>(xps, W_out, b_out, out);
}

// Round 12
// 3930.565 us; speedup vs baseline: 7.2556x; 1.3706x over previous
//
#include <hip/hip_runtime.h>
#include <hip/hip_fp16.h>
#include <math.h>

#define Bsz 64
#define Tsz 1024
#define Isz 128
#define Hsz 512
#define KH  256   // H/2
#define Osz 10

// ---------------------------------------------------------------------------
// Register-tiled fp32 GEMM: C[M,N] = A[M,K] @ Bw[K,N] + bias[N]
// 64x128 block tile, 8x4 micro-tile, 256 threads. Requires M%64==0, N%128==0,
// K%32==0 (holds: K=128/512, N=512/256).
// ---------------------------------------------------------------------------
__global__ __launch_bounds__(256) void gemm_bias_kernel(
    const float* __restrict__ A, const float* __restrict__ Bw,
    const float* __restrict__ bias, float* __restrict__ C,
    int M, int N, int K)
{
  __shared__ float As[32][68];   // [k][m], padded
  const int tid = threadIdx.x;
  const int m0 = blockIdx.x * 64;
  const int n0 = blockIdx.y * 128;
  const int ty = tid >> 5, tx = tid & 31;

  float acc[8][4] = {{0.f}};

  for (int kk = 0; kk < K; kk += 32) {
    __syncthreads();
#pragma unroll
    for (int i = tid; i < 64 * 32; i += 256) {
      int m = i >> 5, k = i & 31;
      As[k][m] = A[(size_t)(m0 + m) * K + kk + k];
    }
    __syncthreads();
#pragma unroll
    for (int k = 0; k < 32; ++k) {
      const float4 bv = *(const float4*)(&Bw[(size_t)(kk + k) * N + n0 + tx * 4]);
      float a[8];
#pragma unroll
      for (int i = 0; i < 8; ++i) a[i] = As[k][ty * 8 + i];
#pragma unroll
      for (int i = 0; i < 8; ++i) {
        acc[i][0] = fmaf(a[i], bv.x, acc[i][0]);
        acc[i][1] = fmaf(a[i], bv.y, acc[i][1]);
        acc[i][2] = fmaf(a[i], bv.z, acc[i][2]);
        acc[i][3] = fmaf(a[i], bv.w, acc[i][3]);
      }
    }
  }

  const float4 bb = *(const float4*)(&bias[n0 + tx * 4]);
#pragma unroll
  for (int i = 0; i < 8; ++i) {
    float4 v;
    v.x = acc[i][0] + bb.x; v.y = acc[i][1] + bb.y;
    v.z = acc[i][2] + bb.z; v.w = acc[i][3] + bb.w;
    *(float4*)(&C[(size_t)(m0 + ty * 8 + i) * N + n0 + tx * 4]) = v;
  }
}

// ---------------------------------------------------------------------------
// i8 dot4
// ---------------------------------------------------------------------------
__device__ __forceinline__ int dot4i8(int a, int b, int acc) {
#if __has_builtin(__builtin_amdgcn_sdot4)
  return __builtin_amdgcn_sdot4(a, b, acc, false);
#else
  acc += ((a << 24) >> 24) * ((b << 24) >> 24);
  acc += ((a << 16) >> 24) * ((b << 16) >> 24);
  acc += ((a << 8)  >> 24) * ((b << 8)  >> 24);
  acc += (a >> 24) * (b >> 24);
  return acc;
#endif
}

// ---------------------------------------------------------------------------
// Quantizer layouts: [G groups x C cols] i8; group g, dword di, byte e covers
// source k = 16g + 4di + e; flat dword index = g*(C*4)+c*4+di.
// ---------------------------------------------------------------------------

// drive: col j = output row of W_rec (512 cols, 32 groups over k=512)
__global__ __launch_bounds__(256) void drive_scale_kernel(
    const float* __restrict__ W_rec, float* __restrict__ CS0)
{
  const int j = blockIdx.x * 256 + threadIdx.x;  // 512
  float m = 0.f;
  for (int k = 0; k < Hsz; ++k)
    m = fmaxf(m, fabsf(W_rec[(size_t)j * Hsz + k]));
  CS0[j] = m;
}

__global__ __launch_bounds__(256) void drive_quant_kernel(
    const float* __restrict__ W_rec, const float* __restrict__ CS0,
    unsigned* __restrict__ Q0)
{
  int i = blockIdx.x * 256 + threadIdx.x;  // 65536 dwords
  if (i >= 32 * Hsz * 4) return;
  int di = i & 3, j = (i >> 2) & 511, g = i >> 11;
  int k0 = 16 * g + 4 * di;
  float ma = CS0[j];
  float r = (ma > 0.f) ? (127.f / ma) : 0.f;
  unsigned out = 0;
#pragma unroll
  for (int e = 0; e < 4; ++e) {
    int q = __float2int_rn(W_rec[(size_t)j * Hsz + k0 + e] * r);
    out |= ((unsigned)(q & 255)) << (8 * e);
  }
  Q0[i] = out;
}

// tau1: col c (256 cols), 32 groups over j=512 (source W1b[j][c])
__global__ __launch_bounds__(256) void tau1_scale_kernel(
    const float* __restrict__ W1b, float* __restrict__ CS1)
{
  const int c = threadIdx.x;  // 256
  float m = 0.f;
  for (int j = 0; j < Hsz; ++j)
    m = fmaxf(m, fabsf(W1b[(size_t)j * KH + c]));
  CS1[c] = m;
}

__global__ __launch_bounds__(256) void tau1_quant_kernel(
    const float* __restrict__ W1b, const float* __restrict__ CS1,
    unsigned* __restrict__ Q1)
{
  int i = blockIdx.x * 256 + threadIdx.x;  // 32768 dwords
  if (i >= 32 * KH * 4) return;
  int di = i & 3, c = (i >> 2) & 255, g = i >> 10;
  int j0 = 16 * g + 4 * di;
  float ma = CS1[c];
  float r = (ma > 0.f) ? (127.f / ma) : 0.f;
  unsigned out = 0;
#pragma unroll
  for (int e = 0; e < 4; ++e) {
    int q = __float2int_rn(W1b[(size_t)(j0 + e) * KH + c] * r);
    out |= ((unsigned)(q & 255)) << (8 * e);
  }
  Q1[i] = out;
}

// tau2: col j (512 cols), 16 groups over k=256 (source W_tau2[k][j])
__global__ __launch_bounds__(256) void tau2_scale_kernel(
    const float* __restrict__ W_tau2, float* __restrict__ CS2)
{
  const int j = blockIdx.x * 256 + threadIdx.x;  // 512
  float m = 0.f;
  for (int k = 0; k < KH; ++k)
    m = fmaxf(m, fabsf(W_tau2[(size_t)k * Hsz + j]));
  CS2[j] = m;
}

__global__ __launch_bounds__(256) void tau2_quant_kernel(
    const float* __restrict__ W_tau2, const float* __restrict__ CS2,
    unsigned* __restrict__ Q2)
{
  int i = blockIdx.x * 256 + threadIdx.x;  // 32768 dwords
  if (i >= 16 * Hsz * 4) return;
  int di = i & 3, j = (i >> 2) & 511, g = i >> 11;
  int k0 = 16 * g + 4 * di;
  float ma = CS2[j];
  float r = (ma > 0.f) ? (127.f / ma) : 0.f;
  unsigned out = 0;
#pragma unroll
  for (int e = 0; e < 4; ++e) {
    int q = __float2int_rn(W_tau2[(size_t)(k0 + e) * Hsz + j] * r);
    out |= ((unsigned)(q & 255)) << (8 * e);
  }
  Q2[i] = out;
}

// ---------------------------------------------------------------------------
// Sequential scan. One WG (512 threads) per batch element. All matvecs i8.
// LDS pin (144 KB dynamic): all 16 tau2 groups (128 KB) + drive g30,g31.
// Phase order vs R11: drive stream MOVED to P3 and fused with the tau2 LDS
// dots, so the tau2/epilogue tail hides under the 240 KB drive stream (drive
// depends only on h, not A). Hq (i8 h) is double-buffered: P3 both reads the
// old h (drive) and writes the new one.
// P1 = tau1 stream (16 groups); 3 barriers/step.
// ---------------------------------------------------------------------------
__global__ __launch_bounds__(512) void scan_kernel(
    float* __restrict__ xps,           // in: xp [B,T,H]; out: hs [B,T,H]
    const float* __restrict__ U,       // [B,T,KH] (b_tau1 already added)
    const unsigned* __restrict__ Q0,   // i8 drive [32][512][4]
    const unsigned* __restrict__ Q1,   // i8 tau1  [32][256][4]
    const unsigned* __restrict__ Q2,   // i8 tau2  [16][512][4]
    const float* __restrict__ CS0,     // [512]
    const float* __restrict__ CS1,     // [256]
    const float* __restrict__ CS2,     // [512]
    const float* __restrict__ bias,    // [H]
    const float* __restrict__ b_tau2)  // [H]
{
  const int b = blockIdx.x;
  const int tid = threadIdx.x;
  const int hs = tid >> 8;             // tau1 k-half
  const int c  = tid & 255;            // tau1 column

  // dynamic LDS: [0..8191] = tau2 groups 0..15; [8192..9215] = drive g30,g31
  extern __shared__ __align__(16) uint4 Wlds[];
  __shared__ __align__(16) int Hq[2][128];       // i8 h, double-buffered
  __shared__ __align__(16) unsigned char Aq[KH]; // i8 A (256 B)
  __shared__ float scaleA[4];                    // per-wave A amax
  __shared__ int parti[2][KH];

  const float bias_r = bias[tid];
  const float bt2_r  = b_tau2[tid];
  const float cs0r = CS0[tid] * (1.0f / 16129.0f);  // /127^2
  const float csr  = CS1[c]   * (1.0f / 16129.0f);
  const float cs2r = CS2[tid] * (1.0f / 16129.0f);
  float hold = 0.f;
  if (tid < 128) { Hq[0][tid] = 0; Hq[1][tid] = 0; }

  float* xprow = xps + (size_t)b * Tsz * Hsz;
  const float* Urow = U + (size_t)b * Tsz * KH;

  const uint4* __restrict__ q0 = (const uint4*)Q0 + tid;                 // stride 512
  const uint4* __restrict__ q1 = (const uint4*)Q1 + (size_t)(hs * 16) * 256 + c; // stride 256
  const uint4* __restrict__ q2 = (const uint4*)Q2 + tid;                 // stride 512
  const uint4* Aq4 = (const uint4*)Aq;

  // --- one-time LDS staging: 16 tau2 groups + drive groups 30,31 ---
#pragma unroll
  for (int i = 0; i < 16; ++i)
    Wlds[i * 512 + tid] = q2[(size_t)i * 512];
#pragma unroll
  for (int i = 0; i < 2; ++i)
    Wlds[8192 + i * 512 + tid] = q0[(size_t)(30 + i) * 512];

  __syncthreads();

  for (int t = 0; t < Tsz; ++t) {
    const uint4* h4 = (const uint4*)Hq[t & 1];

    const float xpv = xprow[tid];
    const float Uv = (tid < KH) ? Urow[tid] : 0.f;

    // --- P1: tau1 partial (i8), 16 streamed groups ---
    int a0 = 0, a1 = 0;
#pragma unroll 8
    for (int g = 0; g < 16; ++g) {
      const uint4 w  = q1[(size_t)g * 256];
      const uint4 hv = h4[hs * 16 + g];
      a0 = dot4i8((int)w.x, (int)hv.x, a0); a1 = dot4i8((int)w.y, (int)hv.y, a1);
      a0 = dot4i8((int)w.z, (int)hv.z, a0); a1 = dot4i8((int)w.w, (int)hv.w, a1);
    }
    parti[hs][c] = a0 + a1;
    __syncthreads();                                   // sync1

    // --- P2: A + per-wave (64-lane segment) quantization ---
    if (tid < KH) {
      float aval = fmaxf(Uv + (float)(parti[0][tid] + parti[1][tid]) * csr, 0.f);
      float m = aval;
#pragma unroll
      for (int off = 32; off >= 1; off >>= 1)
        m = fmaxf(m, __shfl_xor(m, off));
      if ((tid & 63) == 0) scaleA[tid >> 6] = m;
      const float r = (m > 0.f) ? (127.f / m) : 0.f;
      Aq[tid] = (unsigned char)__float2int_rn(aval * r);
    }
    __syncthreads();                                   // sync2

    // --- P3: drive stream (30 groups) fused with tau2 LDS (16 groups) ---
    int d0i = 0, d1i = 0;
    int t2a0 = 0, t2a1 = 0;
    float s = bt2_r;
#pragma unroll
    for (int g = 0; g < 16; ++g) {
      uint4 w0, w1;
      if (g < 15) {
        w0 = q0[(size_t)(2 * g) * 512];
        w1 = q0[(size_t)(2 * g + 1) * 512];
      } else {
        w0 = Wlds[8192 + tid];
        w1 = Wlds[8192 + 512 + tid];
      }
      const uint4 hv0 = h4[2 * g], hv1 = h4[2 * g + 1];
      d0i = dot4i8((int)w0.x, (int)hv0.x, d0i); d1i = dot4i8((int)w0.y, (int)hv0.y, d1i);
      d0i = dot4i8((int)w0.z, (int)hv0.z, d0i); d1i = dot4i8((int)w0.w, (int)hv0.w, d1i);
      d0i = dot4i8((int)w1.x, (int)hv1.x, d0i); d1i = dot4i8((int)w1.y, (int)hv1.y, d1i);
      d0i = dot4i8((int)w1.z, (int)hv1.z, d0i); d1i = dot4i8((int)w1.w, (int)hv1.w, d1i);

      const uint4 wt = Wlds[g * 512 + tid];
      const uint4 av = Aq4[g];
      t2a0 = dot4i8((int)wt.x, (int)av.x, t2a0); t2a1 = dot4i8((int)wt.y, (int)av.y, t2a1);
      t2a0 = dot4i8((int)wt.z, (int)av.z, t2a0); t2a1 = dot4i8((int)wt.w, (int)av.w, t2a1);
      if ((g & 3) == 3) {
        s += (float)(t2a0 + t2a1) * cs2r * scaleA[g >> 2];
        t2a0 = 0; t2a1 = 0;
      }
    }

    // --- epilogue: tau, tanh, Euler update ---
    const float d = xpv + bias_r + (float)(d0i + d1i) * cs0r;
    const float tau = 5.0f + 45.0f / (1.0f + __expf(-s));
    const float e2 = __expf(2.0f * d);
    const float drv = 1.0f - 2.0f / (e2 + 1.0f);       // tanh
    const float hnew = hold + (drv - hold) / tau;
    hold = hnew;
    ((char*)Hq[(t + 1) & 1])[tid] = (char)(__float2int_rn(hnew * 127.f) & 255);
    xprow[tid] = hnew;                                 // hs output (dead xp slot)
    __syncthreads();                                   // sync3

    xprow += Hsz;
    Urow  += KH;
  }
}

// ---------------------------------------------------------------------------
// Epilogue: out[m,o] = hs[m,:] @ W_out[:,o] + b_out[o]
// ---------------------------------------------------------------------------
__global__ __launch_bounds__(256) void outproj_kernel(
    const float* __restrict__ hs, const float* __restrict__ W_out,
    const float* __restrict__ b_out, float* __restrict__ out)
{
  const int m = blockIdx.x * 16 + (threadIdx.x >> 4);
  const int o = threadIdx.x & 15;
  if (o >= Osz) return;
  const float* hrow = hs + (size_t)m * Hsz;
  float acc = b_out[o];
#pragma unroll 8
  for (int kk = 0; kk < Hsz; ++kk)
    acc = fmaf(hrow[kk], W_out[(size_t)kk * Osz + o], acc);
  out[(size_t)m * Osz + o] = acc;
}

// ---------------------------------------------------------------------------
extern "C" void kernel_launch(void* const* d_in, const int* in_sizes, int n_in,
                              void* d_out, int out_size, void* d_ws, size_t ws_size,
                              hipStream_t stream) {
  (void)in_sizes; (void)n_in; (void)out_size; (void)ws_size;

  const float* x      = (const float*)d_in[0];
  const float* W_in   = (const float*)d_in[1];
  const float* b_in   = (const float*)d_in[2];
  const float* W_rec  = (const float*)d_in[3];
  const float* bias   = (const float*)d_in[4];
  const float* W_tau1 = (const float*)d_in[5];
  const float* b_tau1 = (const float*)d_in[6];
  const float* W_tau2 = (const float*)d_in[7];
  const float* b_tau2 = (const float*)d_in[8];
  const float* W_out  = (const float*)d_in[9];
  const float* b_out  = (const float*)d_in[10];
  float* out = (float*)d_out;

  char* ws = (char*)d_ws;
  size_t off = 0;
  float* xps = (float*)(ws + off); off += (size_t)Bsz * Tsz * Hsz * 4;  // 128 MiB
  float* U   = (float*)(ws + off); off += (size_t)Bsz * Tsz * KH * 4;   //  64 MiB
  unsigned* Q0 = (unsigned*)(ws + off); off += (size_t)32 * Hsz * 4 * 4;// 256 KiB
  unsigned* Q1 = (unsigned*)(ws + off); off += (size_t)32 * KH  * 4 * 4;// 128 KiB
  unsigned* Q2 = (unsigned*)(ws + off); off += (size_t)16 * Hsz * 4 * 4;// 128 KiB
  float* CS0   = (float*)(ws + off); off += 512 * 4;
  float* CS1   = (float*)(ws + off); off += 256 * 4;
  float* CS2   = (float*)(ws + off); off += 512 * 4;

  const float* W1b = W_tau1 + (size_t)Hsz * KH;  // rows 512..1023

  const int M = Bsz * Tsz;  // 65536

  // opt-in to 144 KB dynamic LDS for the scan kernel
  (void)hipFuncSetAttribute((const void*)scan_kernel,
                            hipFuncAttributeMaxDynamicSharedMemorySize, 147456);

  // weight quantization
  drive_scale_kernel<<<2, 256, 0, stream>>>(W_rec, CS0);
  drive_quant_kernel<<<256, 256, 0, stream>>>(W_rec, CS0, Q0);
  tau1_scale_kernel<<<1, 256, 0, stream>>>(W1b, CS1);
  tau1_quant_kernel<<<128, 256, 0, stream>>>(W1b, CS1, Q1);
  tau2_scale_kernel<<<2, 256, 0, stream>>>(W_tau2, CS2);
  tau2_quant_kernel<<<128, 256, 0, stream>>>(W_tau2, CS2, Q2);

  // xp = x @ W_in + b_in
  {
    dim3 grid(M / 64, Hsz / 128);
    gemm_bias_kernel<<<grid, 256, 0, stream>>>(x, W_in, b_in, xps, M, Hsz, Isz);
  }
  // U = xp @ W_tau1[:512] + b_tau1
  {
    dim3 grid(M / 64, KH / 128);
    gemm_bias_kernel<<<grid, 256, 0, stream>>>(xps, W_tau1, b_tau1, U, M, KH, Hsz);
  }
  // scan (64 WGs, one per batch element; 144 KB dynamic LDS)
  scan_kernel<<<Bsz, 512, 147456, stream>>>(xps, U, Q0, Q1, Q2,
                                            CS0, CS1, CS2, bias, b_tau2);
  // output projection
  outproj_kernel<<<M / 16, 256, 0, stream>>>(xps, W_out, b_out, out);
}

// Round 13
// 3695.457 us; speedup vs baseline: 7.7173x; 1.0636x over previous
//
#include <hip/hip_runtime.h>
#include <hip/hip_fp16.h>
#include <math.h>

#define Bsz 64
#define Tsz 1024
#define Isz 128
#define Hsz 512
#define KH  256   // H/2
#define Osz 10

// ---------------------------------------------------------------------------
// Register-tiled fp32 GEMM: C[M,N] = A[M,K] @ Bw[K,N] + bias[N]
// 64x128 block tile, 8x4 micro-tile, 256 threads.
// ---------------------------------------------------------------------------
__global__ __launch_bounds__(256) void gemm_bias_kernel(
    const float* __restrict__ A, const float* __restrict__ Bw,
    const float* __restrict__ bias, float* __restrict__ C,
    int M, int N, int K)
{
  __shared__ float As[32][68];   // [k][m], padded
  const int tid = threadIdx.x;
  const int m0 = blockIdx.x * 64;
  const int n0 = blockIdx.y * 128;
  const int ty = tid >> 5, tx = tid & 31;

  float acc[8][4] = {{0.f}};

  for (int kk = 0; kk < K; kk += 32) {
    __syncthreads();
#pragma unroll
    for (int i = tid; i < 64 * 32; i += 256) {
      int m = i >> 5, k = i & 31;
      As[k][m] = A[(size_t)(m0 + m) * K + kk + k];
    }
    __syncthreads();
#pragma unroll
    for (int k = 0; k < 32; ++k) {
      const float4 bv = *(const float4*)(&Bw[(size_t)(kk + k) * N + n0 + tx * 4]);
      float a[8];
#pragma unroll
      for (int i = 0; i < 8; ++i) a[i] = As[k][ty * 8 + i];
#pragma unroll
      for (int i = 0; i < 8; ++i) {
        acc[i][0] = fmaf(a[i], bv.x, acc[i][0]);
        acc[i][1] = fmaf(a[i], bv.y, acc[i][1]);
        acc[i][2] = fmaf(a[i], bv.z, acc[i][2]);
        acc[i][3] = fmaf(a[i], bv.w, acc[i][3]);
      }
    }
  }

  const float4 bb = *(const float4*)(&bias[n0 + tx * 4]);
#pragma unroll
  for (int i = 0; i < 8; ++i) {
    float4 v;
    v.x = acc[i][0] + bb.x; v.y = acc[i][1] + bb.y;
    v.z = acc[i][2] + bb.z; v.w = acc[i][3] + bb.w;
    *(float4*)(&C[(size_t)(m0 + ty * 8 + i) * N + n0 + tx * 4]) = v;
  }
}

// ---------------------------------------------------------------------------
// Wc = W_in @ W1a  (128x512 @ 512x256 -> 128x256), one block per row i.
// ---------------------------------------------------------------------------
__global__ __launch_bounds__(256) void wc_kernel(
    const float* __restrict__ W_in, const float* __restrict__ W1a,
    float* __restrict__ Wc)
{
  __shared__ float row[Hsz];
  const int i = blockIdx.x, c = threadIdx.x;
  for (int h = c; h < Hsz; h += 256) row[h] = W_in[(size_t)i * Hsz + h];
  __syncthreads();
  float acc = 0.f;
#pragma unroll 8
  for (int h = 0; h < Hsz; ++h)
    acc = fmaf(row[h], W1a[(size_t)h * KH + c], acc);
  Wc[(size_t)i * KH + c] = acc;
}

// b_U = b_in @ W1a + b_tau1  (256)
__global__ __launch_bounds__(256) void bu_kernel(
    const float* __restrict__ b_in, const float* __restrict__ W1a,
    const float* __restrict__ b_tau1, float* __restrict__ bU)
{
  const int c = threadIdx.x;
  float acc = b_tau1[c];
#pragma unroll 8
  for (int h = 0; h < Hsz; ++h)
    acc = fmaf(b_in[h], W1a[(size_t)h * KH + c], acc);
  bU[c] = acc;
}

// ---------------------------------------------------------------------------
// i8 dot4
// ---------------------------------------------------------------------------
__device__ __forceinline__ int dot4i8(int a, int b, int acc) {
#if __has_builtin(__builtin_amdgcn_sdot4)
  return __builtin_amdgcn_sdot4(a, b, acc, false);
#else
  acc += ((a << 24) >> 24) * ((b << 24) >> 24);
  acc += ((a << 16) >> 24) * ((b << 16) >> 24);
  acc += ((a << 8)  >> 24) * ((b << 8)  >> 24);
  acc += (a >> 24) * (b >> 24);
  return acc;
#endif
}

// ---------------------------------------------------------------------------
// Quantizer layouts: [G groups x C cols] i8; group g, dword di, byte e covers
// source k = 16g + 4di + e; flat dword index = g*(C*4)+c*4+di.
// ---------------------------------------------------------------------------

// drive: col j = output row of W_rec (512 cols, 32 groups over k=512)
__global__ __launch_bounds__(256) void drive_scale_kernel(
    const float* __restrict__ W_rec, float* __restrict__ CS0)
{
  const int j = blockIdx.x * 256 + threadIdx.x;  // 512
  float m = 0.f;
  for (int k = 0; k < Hsz; ++k)
    m = fmaxf(m, fabsf(W_rec[(size_t)j * Hsz + k]));
  CS0[j] = m;
}

__global__ __launch_bounds__(256) void drive_quant_kernel(
    const float* __restrict__ W_rec, const float* __restrict__ CS0,
    unsigned* __restrict__ Q0)
{
  int i = blockIdx.x * 256 + threadIdx.x;  // 65536 dwords
  if (i >= 32 * Hsz * 4) return;
  int di = i & 3, j = (i >> 2) & 511, g = i >> 11;
  int k0 = 16 * g + 4 * di;
  float ma = CS0[j];
  float r = (ma > 0.f) ? (127.f / ma) : 0.f;
  unsigned out = 0;
#pragma unroll
  for (int e = 0; e < 4; ++e) {
    int q = __float2int_rn(W_rec[(size_t)j * Hsz + k0 + e] * r);
    out |= ((unsigned)(q & 255)) << (8 * e);
  }
  Q0[i] = out;
}

// tau1: col c (256 cols), 32 groups over j=512 (source W1b[j][c])
__global__ __launch_bounds__(256) void tau1_scale_kernel(
    const float* __restrict__ W1b, float* __restrict__ CS1)
{
  const int c = threadIdx.x;  // 256
  float m = 0.f;
  for (int j = 0; j < Hsz; ++j)
    m = fmaxf(m, fabsf(W1b[(size_t)j * KH + c]));
  CS1[c] = m;
}

__global__ __launch_bounds__(256) void tau1_quant_kernel(
    const float* __restrict__ W1b, const float* __restrict__ CS1,
    unsigned* __restrict__ Q1)
{
  int i = blockIdx.x * 256 + threadIdx.x;  // 32768 dwords
  if (i >= 32 * KH * 4) return;
  int di = i & 3, c = (i >> 2) & 255, g = i >> 10;
  int j0 = 16 * g + 4 * di;
  float ma = CS1[c];
  float r = (ma > 0.f) ? (127.f / ma) : 0.f;
  unsigned out = 0;
#pragma unroll
  for (int e = 0; e < 4; ++e) {
    int q = __float2int_rn(W1b[(size_t)(j0 + e) * KH + c] * r);
    out |= ((unsigned)(q & 255)) << (8 * e);
  }
  Q1[i] = out;
}

// tau2: col j (512 cols), 16 groups over k=256 (source W_tau2[k][j])
__global__ __launch_bounds__(256) void tau2_scale_kernel(
    const float* __restrict__ W_tau2, float* __restrict__ CS2)
{
  const int j = blockIdx.x * 256 + threadIdx.x;  // 512
  float m = 0.f;
  for (int k = 0; k < KH; ++k)
    m = fmaxf(m, fabsf(W_tau2[(size_t)k * Hsz + j]));
  CS2[j] = m;
}

__global__ __launch_bounds__(256) void tau2_quant_kernel(
    const float* __restrict__ W_tau2, const float* __restrict__ CS2,
    unsigned* __restrict__ Q2)
{
  int i = blockIdx.x * 256 + threadIdx.x;  // 32768 dwords
  if (i >= 16 * Hsz * 4) return;
  int di = i & 3, j = (i >> 2) & 511, g = i >> 11;
  int k0 = 16 * g + 4 * di;
  float ma = CS2[j];
  float r = (ma > 0.f) ? (127.f / ma) : 0.f;
  unsigned out = 0;
#pragma unroll
  for (int e = 0; e < 4; ++e) {
    int q = __float2int_rn(W_tau2[(size_t)(k0 + e) * Hsz + j] * r);
    out |= ((unsigned)(q & 255)) << (8 * e);
  }
  Q2[i] = out;
}

// ---------------------------------------------------------------------------
// Sequential scan (UNCHANGED from R12 — at ~90% of per-CU L2-fill ceiling).
// One WG (512 threads) per batch element. All matvecs i8. 144 KB dynamic LDS:
// all 16 tau2 groups + drive g30,g31. P3 = drive stream fused with tau2 LDS
// dots + epilogue. Hq double-buffered. 3 barriers/step.
// ---------------------------------------------------------------------------
__global__ __launch_bounds__(512) void scan_kernel(
    float* __restrict__ xps,           // in: xp [B,T,H]; out: hs [B,T,H]
    const float* __restrict__ U,       // [B,T,KH] (b_tau1 already added)
    const unsigned* __restrict__ Q0,   // i8 drive [32][512][4]
    const unsigned* __restrict__ Q1,   // i8 tau1  [32][256][4]
    const unsigned* __restrict__ Q2,   // i8 tau2  [16][512][4]
    const float* __restrict__ CS0,     // [512]
    const float* __restrict__ CS1,     // [256]
    const float* __restrict__ CS2,     // [512]
    const float* __restrict__ bias,    // [H]
    const float* __restrict__ b_tau2)  // [H]
{
  const int b = blockIdx.x;
  const int tid = threadIdx.x;
  const int hs = tid >> 8;             // tau1 k-half
  const int c  = tid & 255;            // tau1 column

  extern __shared__ __align__(16) uint4 Wlds[];
  __shared__ __align__(16) int Hq[2][128];       // i8 h, double-buffered
  __shared__ __align__(16) unsigned char Aq[KH]; // i8 A (256 B)
  __shared__ float scaleA[4];                    // per-wave A amax
  __shared__ int parti[2][KH];

  const float bias_r = bias[tid];
  const float bt2_r  = b_tau2[tid];
  const float cs0r = CS0[tid] * (1.0f / 16129.0f);  // /127^2
  const float csr  = CS1[c]   * (1.0f / 16129.0f);
  const float cs2r = CS2[tid] * (1.0f / 16129.0f);
  float hold = 0.f;
  if (tid < 128) { Hq[0][tid] = 0; Hq[1][tid] = 0; }

  float* xprow = xps + (size_t)b * Tsz * Hsz;
  const float* Urow = U + (size_t)b * Tsz * KH;

  const uint4* __restrict__ q0 = (const uint4*)Q0 + tid;                 // stride 512
  const uint4* __restrict__ q1 = (const uint4*)Q1 + (size_t)(hs * 16) * 256 + c; // stride 256
  const uint4* __restrict__ q2 = (const uint4*)Q2 + tid;                 // stride 512
  const uint4* Aq4 = (const uint4*)Aq;

  // --- one-time LDS staging: 16 tau2 groups + drive groups 30,31 ---
#pragma unroll
  for (int i = 0; i < 16; ++i)
    Wlds[i * 512 + tid] = q2[(size_t)i * 512];
#pragma unroll
  for (int i = 0; i < 2; ++i)
    Wlds[8192 + i * 512 + tid] = q0[(size_t)(30 + i) * 512];

  __syncthreads();

  for (int t = 0; t < Tsz; ++t) {
    const uint4* h4 = (const uint4*)Hq[t & 1];

    const float xpv = xprow[tid];
    const float Uv = (tid < KH) ? Urow[tid] : 0.f;

    // --- P1: tau1 partial (i8), 16 streamed groups ---
    int a0 = 0, a1 = 0;
#pragma unroll 8
    for (int g = 0; g < 16; ++g) {
      const uint4 w  = q1[(size_t)g * 256];
      const uint4 hv = h4[hs * 16 + g];
      a0 = dot4i8((int)w.x, (int)hv.x, a0); a1 = dot4i8((int)w.y, (int)hv.y, a1);
      a0 = dot4i8((int)w.z, (int)hv.z, a0); a1 = dot4i8((int)w.w, (int)hv.w, a1);
    }
    parti[hs][c] = a0 + a1;
    __syncthreads();                                   // sync1

    // --- P2: A + per-wave (64-lane segment) quantization ---
    if (tid < KH) {
      float aval = fmaxf(Uv + (float)(parti[0][tid] + parti[1][tid]) * csr, 0.f);
      float m = aval;
#pragma unroll
      for (int off = 32; off >= 1; off >>= 1)
        m = fmaxf(m, __shfl_xor(m, off));
      if ((tid & 63) == 0) scaleA[tid >> 6] = m;
      const float r = (m > 0.f) ? (127.f / m) : 0.f;
      Aq[tid] = (unsigned char)__float2int_rn(aval * r);
    }
    __syncthreads();                                   // sync2

    // --- P3: drive stream (30 groups) fused with tau2 LDS (16 groups) ---
    int d0i = 0, d1i = 0;
    int t2a0 = 0, t2a1 = 0;
    float s = bt2_r;
#pragma unroll
    for (int g = 0; g < 16; ++g) {
      uint4 w0, w1;
      if (g < 15) {
        w0 = q0[(size_t)(2 * g) * 512];
        w1 = q0[(size_t)(2 * g + 1) * 512];
      } else {
        w0 = Wlds[8192 + tid];
        w1 = Wlds[8192 + 512 + tid];
      }
      const uint4 hv0 = h4[2 * g], hv1 = h4[2 * g + 1];
      d0i = dot4i8((int)w0.x, (int)hv0.x, d0i); d1i = dot4i8((int)w0.y, (int)hv0.y, d1i);
      d0i = dot4i8((int)w0.z, (int)hv0.z, d0i); d1i = dot4i8((int)w0.w, (int)hv0.w, d1i);
      d0i = dot4i8((int)w1.x, (int)hv1.x, d0i); d1i = dot4i8((int)w1.y, (int)hv1.y, d1i);
      d0i = dot4i8((int)w1.z, (int)hv1.z, d0i); d1i = dot4i8((int)w1.w, (int)hv1.w, d1i);

      const uint4 wt = Wlds[g * 512 + tid];
      const uint4 av = Aq4[g];
      t2a0 = dot4i8((int)wt.x, (int)av.x, t2a0); t2a1 = dot4i8((int)wt.y, (int)av.y, t2a1);
      t2a0 = dot4i8((int)wt.z, (int)av.z, t2a0); t2a1 = dot4i8((int)wt.w, (int)av.w, t2a1);
      if ((g & 3) == 3) {
        s += (float)(t2a0 + t2a1) * cs2r * scaleA[g >> 2];
        t2a0 = 0; t2a1 = 0;
      }
    }

    // --- epilogue: tau, tanh, Euler update ---
    const float d = xpv + bias_r + (float)(d0i + d1i) * cs0r;
    const float tau = 5.0f + 45.0f / (1.0f + __expf(-s));
    const float e2 = __expf(2.0f * d);
    const float drv = 1.0f - 2.0f / (e2 + 1.0f);       // tanh
    const float hnew = hold + (drv - hold) / tau;
    hold = hnew;
    ((char*)Hq[(t + 1) & 1])[tid] = (char)(__float2int_rn(hnew * 127.f) & 255);
    xprow[tid] = hnew;                                 // hs output (dead xp slot)
    __syncthreads();                                   // sync3

    xprow += Hsz;
    Urow  += KH;
  }
}

// ---------------------------------------------------------------------------
// Epilogue: out[m,o] = hs[m,:] @ W_out[:,o] + b_out[o].
// 16 rows/block staged to LDS via coalesced float4 (+4 pad to spread banks);
// W_out also in LDS. Inner loop = b128 LDS h-reads + scalar LDS W + FMA.
// ---------------------------------------------------------------------------
__global__ __launch_bounds__(256) void outproj_kernel(
    const float* __restrict__ hs, const float* __restrict__ W_out,
    const float* __restrict__ b_out, float* __restrict__ out)
{
  __shared__ float hsL[16][516];       // 516 = 512+4: rows spread across banks
  __shared__ float WL[Hsz * Osz];      // 20 KB
  const int tid = threadIdx.x;
  const size_t m0 = (size_t)blockIdx.x * 16;

  for (int i = tid; i < Hsz * Osz; i += 256) WL[i] = W_out[i];

  const float4* src = (const float4*)(hs + m0 * Hsz);  // 2048 float4, contiguous
#pragma unroll
  for (int i = 0; i < 8; ++i) {
    int idx = i * 256 + tid;
    *(float4*)&hsL[idx >> 7][(idx & 127) * 4] = src[idx];
  }
  __syncthreads();

  const int r = tid >> 4, o = tid & 15;
  if (o < Osz) {
    float acc = b_out[o];
#pragma unroll 8
    for (int k4 = 0; k4 < 128; ++k4) {
      const float4 h4 = *(const float4*)&hsL[r][k4 * 4];
      acc = fmaf(h4.x, WL[(4 * k4 + 0) * Osz + o], acc);
      acc = fmaf(h4.y, WL[(4 * k4 + 1) * Osz + o], acc);
      acc = fmaf(h4.z, WL[(4 * k4 + 2) * Osz + o], acc);
      acc = fmaf(h4.w, WL[(4 * k4 + 3) * Osz + o], acc);
    }
    out[(m0 + r) * Osz + o] = acc;
  }
}

// ---------------------------------------------------------------------------
extern "C" void kernel_launch(void* const* d_in, const int* in_sizes, int n_in,
                              void* d_out, int out_size, void* d_ws, size_t ws_size,
                              hipStream_t stream) {
  (void)in_sizes; (void)n_in; (void)out_size; (void)ws_size;

  const float* x      = (const float*)d_in[0];
  const float* W_in   = (const float*)d_in[1];
  const float* b_in   = (const float*)d_in[2];
  const float* W_rec  = (const float*)d_in[3];
  const float* bias   = (const float*)d_in[4];
  const float* W_tau1 = (const float*)d_in[5];
  const float* b_tau1 = (const float*)d_in[6];
  const float* W_tau2 = (const float*)d_in[7];
  const float* b_tau2 = (const float*)d_in[8];
  const float* W_out  = (const float*)d_in[9];
  const float* b_out  = (const float*)d_in[10];
  float* out = (float*)d_out;

  char* ws = (char*)d_ws;
  size_t off = 0;
  float* xps = (float*)(ws + off); off += (size_t)Bsz * Tsz * Hsz * 4;  // 128 MiB
  float* U   = (float*)(ws + off); off += (size_t)Bsz * Tsz * KH * 4;   //  64 MiB
  unsigned* Q0 = (unsigned*)(ws + off); off += (size_t)32 * Hsz * 4 * 4;// 256 KiB
  unsigned* Q1 = (unsigned*)(ws + off); off += (size_t)32 * KH  * 4 * 4;// 128 KiB
  unsigned* Q2 = (unsigned*)(ws + off); off += (size_t)16 * Hsz * 4 * 4;// 128 KiB
  float* CS0   = (float*)(ws + off); off += 512 * 4;
  float* CS1   = (float*)(ws + off); off += 256 * 4;
  float* CS2   = (float*)(ws + off); off += 512 * 4;
  float* Wc    = (float*)(ws + off); off += (size_t)Isz * KH * 4;       // 128 KiB
  float* bU    = (float*)(ws + off); off += 256 * 4;

  const float* W1a = W_tau1;                     // rows 0..511
  const float* W1b = W_tau1 + (size_t)Hsz * KH;  // rows 512..1023

  const int M = Bsz * Tsz;  // 65536

  // opt-in to 144 KB dynamic LDS for the scan kernel
  (void)hipFuncSetAttribute((const void*)scan_kernel,
                            hipFuncAttributeMaxDynamicSharedMemorySize, 147456);

  // weight quantization + fused-U weight precompute (all small, independent)
  drive_scale_kernel<<<2, 256, 0, stream>>>(W_rec, CS0);
  drive_quant_kernel<<<256, 256, 0, stream>>>(W_rec, CS0, Q0);
  tau1_scale_kernel<<<1, 256, 0, stream>>>(W1b, CS1);
  tau1_quant_kernel<<<128, 256, 0, stream>>>(W1b, CS1, Q1);
  tau2_scale_kernel<<<2, 256, 0, stream>>>(W_tau2, CS2);
  tau2_quant_kernel<<<128, 256, 0, stream>>>(W_tau2, CS2, Q2);
  wc_kernel<<<Isz, 256, 0, stream>>>(W_in, W1a, Wc);
  bu_kernel<<<1, 256, 0, stream>>>(b_in, W1a, b_tau1, bU);

  // xp = x @ W_in + b_in            [65536,128]@[128,512]
  {
    dim3 grid(M / 64, Hsz / 128);
    gemm_bias_kernel<<<grid, 256, 0, stream>>>(x, W_in, b_in, xps, M, Hsz, Isz);
  }
  // U = x @ Wc + bU                 [65536,128]@[128,256]  (== xp@W1a + b_tau1)
  {
    dim3 grid(M / 64, KH / 128);
    gemm_bias_kernel<<<grid, 256, 0, stream>>>(x, Wc, bU, U, M, KH, Isz);
  }
  // scan (64 WGs, one per batch element; 144 KB dynamic LDS)
  scan_kernel<<<Bsz, 512, 147456, stream>>>(xps, U, Q0, Q1, Q2,
                                            CS0, CS1, CS2, bias, b_tau2);
  // output projection
  outproj_kernel<<<M / 16, 256, 0, stream>>>(xps, W_out, b_out, out);
}